// Round 1
// baseline (800.176 us; speedup 1.0000x reference)
//
#include <hip/hip_runtime.h>
#include <math.h>

#define NQ_    65536
#define NV_    1558
#define HALF_V 779

// ws layout in floats (total 4,452,352 floats = 17.8 MB)
#define WS_STATS 0
#define WS_GFC   512
#define WS_GTH   1280
#define WS_VF    15360
#define WS_C3A   65536
#define WS_C3B   151552
#define WS_C4A   323584
#define WS_C4B   1699840

// ---------------- bilinear feature sampling (vertices) ----------------
__device__ __forceinline__ void bsample(const float* __restrict__ f, int C, int H, int W,
                                        float xn, float yn, float* __restrict__ o) {
    float x = (xn + 1.f) * 0.5f * (float)(W - 1);
    float y = (yn + 1.f) * 0.5f * (float)(H - 1);
    float x0f = floorf(x), y0f = floorf(y);
    float wx = x - x0f, wy = y - y0f;
    int x0 = (int)fminf(fmaxf(x0f, 0.f), (float)(W - 1));
    int x1 = (int)fminf(fmaxf(x0f + 1.f, 0.f), (float)(W - 1));
    int y0 = (int)fminf(fmaxf(y0f, 0.f), (float)(H - 1));
    int y1 = (int)fminf(fmaxf(y0f + 1.f, 0.f), (float)(H - 1));
    for (int c = 0; c < C; ++c) {
        const float* b = f + c * H * W;
        float v00 = b[y0 * W + x0], v01 = b[y0 * W + x1];
        float v10 = b[y1 * W + x0], v11 = b[y1 * W + x1];
        o[c] = v00 * (1.f - wx) * (1.f - wy) + v01 * wx * (1.f - wy)
             + v10 * (1.f - wx) * wy       + v11 * wx * wy;
    }
}

__global__ void feat_sample_k(const float* __restrict__ vert_xy,
                              const float* __restrict__ img,
                              const float* __restrict__ ft1,
                              float* __restrict__ vf) {
    int v = blockIdx.x * 64 + threadIdx.x;
    if (v >= NV_) return;
    float xn = vert_xy[v * 2 + 0], yn = vert_xy[v * 2 + 1];
    float tmp[8];
    bsample(img, 3, 256, 256, xn, yn, tmp);
    float* o = vf + v * 32;
    o[0] = tmp[0]; o[1] = tmp[1]; o[2] = tmp[2];
    bsample(ft1, 8, 64, 64, xn, yn, tmp);
    #pragma unroll
    for (int c = 0; c < 8; ++c) o[3 + c] = tmp[c];
}

// ---------------- conv2d 3x3 pad1 + per-channel sum/sumsq partials ----------------
__global__ __launch_bounds__(256) void conv2d_stats_k(
    const float* __restrict__ in, const float* __restrict__ w,
    float* __restrict__ out, float* __restrict__ stats,
    int Cin, int H, int W, int bpc) {
    int c = (int)(blockIdx.x) / bpc;
    int pix = ((int)(blockIdx.x) % bpc) * 256 + threadIdx.x;
    int HW = H * W;
    int y = pix / W, x = pix % W;
    float acc = 0.f;
    const float* wc = w + c * Cin * 9;
    for (int i = 0; i < Cin; ++i) {
        const float* ip = in + i * HW;
        const float* wi = wc + i * 9;
        #pragma unroll
        for (int dy = 0; dy < 3; ++dy) {
            int yy = y + dy - 1;
            if (yy < 0 || yy >= H) continue;
            #pragma unroll
            for (int dx = 0; dx < 3; ++dx) {
                int xx = x + dx - 1;
                if (xx < 0 || xx >= W) continue;
                acc = fmaf(wi[dy * 3 + dx], ip[yy * W + xx], acc);
            }
        }
    }
    out[c * HW + pix] = acc;
    __shared__ float rs[256], rq[256];
    rs[threadIdx.x] = acc;
    rq[threadIdx.x] = acc * acc;
    __syncthreads();
    for (int s = 128; s > 0; s >>= 1) {
        if (threadIdx.x < s) { rs[threadIdx.x] += rs[threadIdx.x + s]; rq[threadIdx.x] += rq[threadIdx.x + s]; }
        __syncthreads();
    }
    if (threadIdx.x == 0) {
        atomicAdd(&stats[c * 2 + 0], rs[0]);
        atomicAdd(&stats[c * 2 + 1], rq[0]);
    }
}

__global__ void ln_finalize_k(float* __restrict__ stats, int C, float invHW) {
    int c = threadIdx.x;
    if (c >= C) return;
    float s = stats[c * 2], s2 = stats[c * 2 + 1];
    float m = s * invHW;
    float var = s2 * invHW - m * m;
    if (var < 0.f) var = 0.f;
    stats[c * 2 + 0] = m;
    stats[c * 2 + 1] = rsqrtf(var + 1e-6f);
}

__global__ __launch_bounds__(256) void ln_apply_k(
    float* __restrict__ buf, const float* __restrict__ stats,
    const float* __restrict__ g, const float* __restrict__ b, int HW) {
    int i = blockIdx.x * 256 + threadIdx.x;
    int c = i / HW;      // HW is a power of two
    int hw = i % HW;
    float m = stats[c * 2], inv = stats[c * 2 + 1];
    float x = buf[i];
    float r = fmaf((x - m) * inv, g[hw], b[hw]);
    buf[i] = fmaxf(r, 0.f);
}

// ---------------- adaptive 3x3 avg pool -> gf_cat[c][colOff + bin] ----------------
__global__ __launch_bounds__(256) void apool3_k(const float* __restrict__ in,
                                                float* __restrict__ gfc,
                                                int H, int W, int colOff) {
    int c = (int)blockIdx.x / 9;
    int bin = (int)blockIdx.x % 9;
    int bh = bin / 3, bw = bin % 3;
    int hs = bh * H / 3, he = ((bh + 1) * H + 2) / 3;
    int wsx = bw * W / 3, we = ((bw + 1) * W + 2) / 3;
    int rw = we - wsx, rh = he - hs, n = rw * rh;
    const float* b = in + c * H * W;
    float s = 0.f;
    for (int t = threadIdx.x; t < n; t += 256) {
        int iy = t / rw, ix = t % rw;
        s += b[(hs + iy) * W + (wsx + ix)];
    }
    __shared__ float rs[256];
    rs[threadIdx.x] = s;
    __syncthreads();
    for (int st = 128; st > 0; st >>= 1) {
        if (threadIdx.x < st) rs[threadIdx.x] += rs[threadIdx.x + st];
        __syncthreads();
    }
    if (threadIdx.x == 0) gfc[c * 18 + colOff + bin] = rs[0] / (float)n;
}

// ---------------- conv1d (42->779) + LN(18) + relu ----------------
__global__ __launch_bounds__(64) void gt1_k(const float* __restrict__ gfc,
                                            const float* __restrict__ w,
                                            const float* __restrict__ g,
                                            const float* __restrict__ b,
                                            float* __restrict__ outh) {
    int o = blockIdx.x;     // 779
    int p = threadIdx.x;
    __shared__ float vals[18];
    if (p < 18) {
        float acc = 0.f;
        const float* wo = w + o * 42 * 3;
        for (int c = 0; c < 42; ++c) {
            const float* gr = gfc + c * 18;
            #pragma unroll
            for (int k = 0; k < 3; ++k) {
                int pk = p + k - 1;
                if (pk >= 0 && pk < 18) acc = fmaf(wo[c * 3 + k], gr[pk], acc);
            }
        }
        vals[p] = acc;
    }
    __syncthreads();
    if (p < 18) {
        float s = 0.f, s2 = 0.f;
        #pragma unroll
        for (int j = 0; j < 18; ++j) { float x = vals[j]; s += x; s2 += x * x; }
        float m = s / 18.f;
        float var = s2 / 18.f - m * m;
        if (var < 0.f) var = 0.f;
        float inv = rsqrtf(var + 1e-6f);
        float r = fmaf((vals[p] - m) * inv, g[p], b[p]);
        outh[o * 18 + p] = fmaxf(r, 0.f);
    }
}

// ---------------- conv1d (779->1558) + LN(18) + relu -> vf cols 11..28 ----------------
__global__ __launch_bounds__(64) void gt2_k(const float* __restrict__ h,
                                            const float* __restrict__ w,
                                            const float* __restrict__ g,
                                            const float* __restrict__ b,
                                            float* __restrict__ vf) {
    int o = blockIdx.x;     // 1558
    int lane = threadIdx.x;
    float part[18];
    #pragma unroll
    for (int p = 0; p < 18; ++p) part[p] = 0.f;
    for (int c = lane; c < HALF_V; c += 64) {
        const float* wr = w + (o * HALF_V + c) * 3;
        float w0 = wr[0], w1 = wr[1], w2 = wr[2];
        const float* hr = h + c * 18;
        float hv[18];
        #pragma unroll
        for (int p = 0; p < 18; ++p) hv[p] = hr[p];
        #pragma unroll
        for (int p = 0; p < 18; ++p) {
            float a = w1 * hv[p];
            if (p > 0)  a = fmaf(w0, hv[p - 1], a);
            if (p < 17) a = fmaf(w2, hv[p + 1], a);
            part[p] += a;
        }
    }
    #pragma unroll
    for (int p = 0; p < 18; ++p) {
        float vv = part[p];
        for (int off = 32; off > 0; off >>= 1) vv += __shfl_xor(vv, off, 64);
        part[p] = vv;
    }
    float s = 0.f, s2 = 0.f;
    #pragma unroll
    for (int p = 0; p < 18; ++p) { s += part[p]; s2 += part[p] * part[p]; }
    float m = s / 18.f;
    float var = s2 / 18.f - m * m;
    if (var < 0.f) var = 0.f;
    float inv = rsqrtf(var + 1e-6f);
    if (lane < 18) {
        float r = fmaf((part[lane] - m) * inv, g[lane], b[lane]);
        vf[o * 32 + 11 + lane] = fmaxf(r, 0.f);
    }
}

// ---------------- fused per-query: argmin + gather + attention MLP + out MLP ----------------
__global__ __launch_bounds__(256) void fuse_k(
    const float* __restrict__ v, const float* __restrict__ vert,
    const float* __restrict__ vvis, const float* __restrict__ qvis,
    const float* __restrict__ ixy, const float* __restrict__ fxy,
    const float* __restrict__ lat, const float* __restrict__ vf,
    const float* __restrict__ atw1, const float* __restrict__ atw2,
    const float* __restrict__ fcw1, const float* __restrict__ fcw2,
    float* __restrict__ out) {
    __shared__ float4 sv[NV_];
    int tid = threadIdx.x;
    for (int i = tid; i < NV_; i += 256) {
        float x = vert[i * 3 + 0], y = vert[i * 3 + 1], z = vert[i * 3 + 2];
        float pn = __fadd_rn(__fadd_rn(__fmul_rn(x, x), __fmul_rn(y, y)), __fmul_rn(z, z));
        sv[i] = make_float4(x, y, z, pn);
    }
    __syncthreads();
    int q = blockIdx.x * 256 + tid;
    float vx = v[q * 3 + 0], vy = v[q * 3 + 1], vz = v[q * 3 + 2];
    float vn = __fadd_rn(__fadd_rn(__fmul_rn(vx, vx), __fmul_rn(vy, vy)), __fmul_rn(vz, vz));
    float best = 3.4e38f;
    int bi = 0;
    // d2 = (|v|^2 + |p|^2) - 2*(v.p), np-rounding preserved (no fma contraction)
    for (int p = 0; p < NV_; ++p) {
        float4 pv = sv[p];
        float dot = __fadd_rn(__fadd_rn(__fmul_rn(vx, pv.x), __fmul_rn(vy, pv.y)), __fmul_rn(vz, pv.z));
        float d2 = __fsub_rn(__fadd_rn(vn, pv.w), __fmul_rn(2.f, dot));
        if (d2 < best) { best = d2; bi = p; }
    }
    int bi2 = bi + HALF_V; if (bi2 >= NV_) bi2 -= NV_;
    const float* f    = vf + bi * 32;
    const float* ftoh = vf + bi2 * 32;
    float vis = vvis[bi], vist = vvis[bi2];

    float yv[96];
    yv[0] = ixy[q * 3 + 0]; yv[1] = ixy[q * 3 + 1]; yv[2] = ixy[q * 3 + 2];
    #pragma unroll
    for (int j = 0; j < 8; ++j) yv[3 + j] = fxy[q * 8 + j];
    #pragma unroll
    for (int j = 0; j < 11; ++j) yv[11 + j] = f[j] * vis;
    #pragma unroll
    for (int j = 0; j < 11; ++j) yv[22 + j] = ftoh[j] * vist;
    #pragma unroll
    for (int j = 0; j < 18; ++j) yv[33 + j] = f[11 + j] * vis;
    #pragma unroll
    for (int j = 0; j < 18; ++j) yv[51 + j] = ftoh[11 + j] * vist;
    #pragma unroll
    for (int j = 0; j < 24; ++j) yv[69 + j] = lat[q * 24 + j];
    yv[93] = qvis[q]; yv[94] = vis; yv[95] = vist;

    float h[96];
    #pragma unroll
    for (int o = 0; o < 96; o += 8) {
        float acc[8];
        #pragma unroll
        for (int j = 0; j < 8; ++j) acc[j] = 0.f;
        #pragma unroll
        for (int c = 0; c < 96; ++c) {
            float yc = yv[c];
            #pragma unroll
            for (int j = 0; j < 8; ++j) acc[j] = fmaf(atw1[(o + j) * 96 + c], yc, acc[j]);
        }
        #pragma unroll
        for (int j = 0; j < 8; ++j) h[o + j] = fmaxf(acc[j], 0.f);
    }
    float at6[6];
    #pragma unroll
    for (int o = 0; o < 6; ++o) {
        float acc = 0.f;
        #pragma unroll
        for (int c = 0; c < 96; ++c) acc = fmaf(atw2[o * 96 + c], h[c], acc);
        at6[o] = 1.f / (1.f + expf(-acc));
    }
    #pragma unroll
    for (int j = 0; j < 11; ++j) yv[j]      *= at6[0];
    #pragma unroll
    for (int j = 0; j < 11; ++j) yv[11 + j] *= at6[1];
    #pragma unroll
    for (int j = 0; j < 11; ++j) yv[22 + j] *= at6[2];
    #pragma unroll
    for (int j = 0; j < 18; ++j) yv[33 + j] *= at6[3];
    #pragma unroll
    for (int j = 0; j < 18; ++j) yv[51 + j] *= at6[4];
    #pragma unroll
    for (int j = 0; j < 24; ++j) yv[69 + j] *= at6[5];
    // yv[93..95] unscaled

    #pragma unroll
    for (int o = 0; o < 96; o += 8) {
        float acc[8];
        #pragma unroll
        for (int j = 0; j < 8; ++j) acc[j] = 0.f;
        #pragma unroll
        for (int c = 0; c < 96; ++c) {
            float yc = yv[c];
            #pragma unroll
            for (int j = 0; j < 8; ++j) acc[j] = fmaf(fcw1[(o + j) * 96 + c], yc, acc[j]);
        }
        #pragma unroll
        for (int j = 0; j < 8; ++j) h[o + j] = fmaxf(acc[j], 0.f);
    }
    #pragma unroll
    for (int o = 0; o < 40; o += 8) {
        float acc[8];
        #pragma unroll
        for (int j = 0; j < 8; ++j) acc[j] = 0.f;
        #pragma unroll
        for (int c = 0; c < 96; ++c) {
            float hc = h[c];
            #pragma unroll
            for (int j = 0; j < 8; ++j) acc[j] = fmaf(fcw2[(o + j) * 96 + c], hc, acc[j]);
        }
        #pragma unroll
        for (int j = 0; j < 8; ++j) out[q * 40 + o + j] = acc[j];
    }
}

extern "C" void kernel_launch(void* const* d_in, const int* in_sizes, int n_in,
                              void* d_out, int out_size, void* d_ws, size_t ws_size,
                              hipStream_t stream) {
    const float* vert_xy = (const float*)d_in[0];
    const float* ft1     = (const float*)d_in[1];
    const float* ft_xy   = (const float*)d_in[2];
    const float* vert    = (const float*)d_in[3];
    const float* v       = (const float*)d_in[4];
    const float* vvis    = (const float*)d_in[5];
    const float* qvis    = (const float*)d_in[6];
    const float* ixy     = (const float*)d_in[7];
    const float* img     = (const float*)d_in[8];
    const float* lat     = (const float*)d_in[9];
    const float* fcw1    = (const float*)d_in[10];
    const float* fcw2    = (const float*)d_in[11];
    const float* atw1    = (const float*)d_in[12];
    const float* atw2    = (const float*)d_in[13];
    const float* gtw1    = (const float*)d_in[14];
    const float* gtg1    = (const float*)d_in[15];
    const float* gtb1    = (const float*)d_in[16];
    const float* gtw2    = (const float*)d_in[17];
    const float* gtg2    = (const float*)d_in[18];
    const float* gtb2    = (const float*)d_in[19];
    const float* c3w1    = (const float*)d_in[20];
    const float* c3g1    = (const float*)d_in[21];
    const float* c3b1    = (const float*)d_in[22];
    const float* c3w2    = (const float*)d_in[23];
    const float* c3g2    = (const float*)d_in[24];
    const float* c3b2    = (const float*)d_in[25];
    const float* c4w1    = (const float*)d_in[26];
    const float* c4g1    = (const float*)d_in[27];
    const float* c4b1    = (const float*)d_in[28];
    const float* c4w2    = (const float*)d_in[29];
    const float* c4g2    = (const float*)d_in[30];
    const float* c4b2    = (const float*)d_in[31];
    float* out = (float*)d_out;
    float* ws  = (float*)d_ws;
    float* stats = ws + WS_STATS;
    float* gfc   = ws + WS_GFC;
    float* gth   = ws + WS_GTH;
    float* vfb   = ws + WS_VF;
    float* c3a   = ws + WS_C3A;
    float* c3bb  = ws + WS_C3B;
    float* c4a   = ws + WS_C4A;
    float* c4bb  = ws + WS_C4B;

    hipMemsetAsync(stats, 0, 512 * sizeof(float), stream);

    feat_sample_k<<<25, 64, 0, stream>>>(vert_xy, img, ft1, vfb);

    // c3 chain: ft1 (8,64,64) -> (21) -> (42) -> pool -> gfc cols 9..17
    conv2d_stats_k<<<21 * 16, 256, 0, stream>>>(ft1, c3w1, c3a, stats + 0, 8, 64, 64, 16);
    ln_finalize_k<<<1, 64, 0, stream>>>(stats + 0, 21, 1.f / 4096.f);
    ln_apply_k<<<21 * 16, 256, 0, stream>>>(c3a, stats + 0, c3g1, c3b1, 4096);
    conv2d_stats_k<<<42 * 16, 256, 0, stream>>>(c3a, c3w2, c3bb, stats + 128, 21, 64, 64, 16);
    ln_finalize_k<<<1, 64, 0, stream>>>(stats + 128, 42, 1.f / 4096.f);
    ln_apply_k<<<42 * 16, 256, 0, stream>>>(c3bb, stats + 128, c3g2, c3b2, 4096);
    apool3_k<<<42 * 9, 256, 0, stream>>>(c3bb, gfc, 64, 64, 9);

    // c4 chain: img (3,256,256) -> (21) -> (42) -> pool -> gfc cols 0..8
    conv2d_stats_k<<<21 * 256, 256, 0, stream>>>(img, c4w1, c4a, stats + 256, 3, 256, 256, 256);
    ln_finalize_k<<<1, 64, 0, stream>>>(stats + 256, 21, 1.f / 65536.f);
    ln_apply_k<<<21 * 256, 256, 0, stream>>>(c4a, stats + 256, c4g1, c4b1, 65536);
    conv2d_stats_k<<<42 * 256, 256, 0, stream>>>(c4a, c4w2, c4bb, stats + 384, 21, 256, 256, 256);
    ln_finalize_k<<<1, 64, 0, stream>>>(stats + 384, 42, 1.f / 65536.f);
    ln_apply_k<<<42 * 256, 256, 0, stream>>>(c4bb, stats + 384, c4g2, c4b2, 65536);
    apool3_k<<<42 * 9, 256, 0, stream>>>(c4bb, gfc, 256, 256, 0);

    // global-token conv1d stack -> vf cols 11..28
    gt1_k<<<779, 64, 0, stream>>>(gfc, gtw1, gtg1, gtb1, gth);
    gt2_k<<<1558, 64, 0, stream>>>(gth, gtw2, gtg2, gtb2, vfb);

    // fused per-query path
    fuse_k<<<256, 256, 0, stream>>>(v, vert, vvis, qvis, ixy, ft_xy, lat, vfb,
                                    atw1, atw2, fcw1, fcw2, out);
}

// Round 2
// 675.326 us; speedup vs baseline: 1.1849x; 1.1849x over previous
//
#include <hip/hip_runtime.h>
#include <math.h>

#define NQ_    65536
#define NV_    1558
#define HALF_V 779
#define QPB    64     // queries per mlp block
#define YVS    100    // padded yv stride (breaks 96-stride LDS bank aliasing)

// ws layout in floats (total 4,452,352 floats = 17.8 MB, same as round 1)
#define WS_STATS 0          //   512
#define WS_GFC   512        //   768
#define WS_GTH   1280       // 14080
#define WS_VF    15360      // 50176
#define WS_C3A   65536      // 86016   (also reused for c4 conv stat partials)
#define WS_C3B   151552     // 172032
#define WS_C4A   323584     // 1376256 (also reused for c3 conv stat partials)
#define WS_C4B   1699840    // 2752512 (also reused for idx[] after apool(c4))

// ---------------- bilinear feature sampling (vertices) ----------------
__device__ __forceinline__ void bsample(const float* __restrict__ f, int C, int H, int W,
                                        float xn, float yn, float* __restrict__ o) {
    float x = (xn + 1.f) * 0.5f * (float)(W - 1);
    float y = (yn + 1.f) * 0.5f * (float)(H - 1);
    float x0f = floorf(x), y0f = floorf(y);
    float wx = x - x0f, wy = y - y0f;
    int x0 = (int)fminf(fmaxf(x0f, 0.f), (float)(W - 1));
    int x1 = (int)fminf(fmaxf(x0f + 1.f, 0.f), (float)(W - 1));
    int y0 = (int)fminf(fmaxf(y0f, 0.f), (float)(H - 1));
    int y1 = (int)fminf(fmaxf(y0f + 1.f, 0.f), (float)(H - 1));
    for (int c = 0; c < C; ++c) {
        const float* b = f + c * H * W;
        float v00 = b[y0 * W + x0], v01 = b[y0 * W + x1];
        float v10 = b[y1 * W + x0], v11 = b[y1 * W + x1];
        o[c] = v00 * (1.f - wx) * (1.f - wy) + v01 * wx * (1.f - wy)
             + v10 * (1.f - wx) * wy       + v11 * wx * wy;
    }
}

__global__ void feat_sample_k(const float* __restrict__ vert_xy,
                              const float* __restrict__ img,
                              const float* __restrict__ ft1,
                              float* __restrict__ vf) {
    int v = blockIdx.x * 64 + threadIdx.x;
    if (v >= NV_) return;
    float xn = vert_xy[v * 2 + 0], yn = vert_xy[v * 2 + 1];
    float tmp[8];
    bsample(img, 3, 256, 256, xn, yn, tmp);
    float* o = vf + v * 32;
    o[0] = tmp[0]; o[1] = tmp[1]; o[2] = tmp[2];
    bsample(ft1, 8, 64, 64, xn, yn, tmp);
    #pragma unroll
    for (int c = 0; c < 8; ++c) o[3 + c] = tmp[c];
}

// ---------------- conv2d 3x3 pad1 + per-channel per-block sum/sumsq partials ----------------
__global__ __launch_bounds__(256) void conv2d_stats_k(
    const float* __restrict__ in, const float* __restrict__ w,
    float* __restrict__ out, float* __restrict__ part,
    int Cin, int H, int W, int bpc) {
    int c = (int)(blockIdx.x) / bpc;
    int pb = (int)(blockIdx.x) % bpc;
    int pix = pb * 256 + threadIdx.x;
    int HW = H * W;
    int y = pix / W, x = pix % W;
    float acc = 0.f;
    const float* wc = w + c * Cin * 9;
    for (int i = 0; i < Cin; ++i) {
        const float* ip = in + i * HW;
        const float* wi = wc + i * 9;
        #pragma unroll
        for (int dy = 0; dy < 3; ++dy) {
            int yy = y + dy - 1;
            if (yy < 0 || yy >= H) continue;
            #pragma unroll
            for (int dx = 0; dx < 3; ++dx) {
                int xx = x + dx - 1;
                if (xx < 0 || xx >= W) continue;
                acc = fmaf(wi[dy * 3 + dx], ip[yy * W + xx], acc);
            }
        }
    }
    out[c * HW + pix] = acc;
    __shared__ float rs[256], rq[256];
    rs[threadIdx.x] = acc;
    rq[threadIdx.x] = acc * acc;
    __syncthreads();
    for (int s = 128; s > 0; s >>= 1) {
        if (threadIdx.x < s) { rs[threadIdx.x] += rs[threadIdx.x + s]; rq[threadIdx.x] += rq[threadIdx.x + s]; }
        __syncthreads();
    }
    if (threadIdx.x == 0) {
        part[(c * bpc + pb) * 2 + 0] = rs[0];
        part[(c * bpc + pb) * 2 + 1] = rq[0];
    }
}

__global__ void ln_finalize_k(const float* __restrict__ part, float* __restrict__ stats,
                              int C, int nb, float invHW) {
    int c = threadIdx.x;
    if (c >= C) return;
    float s = 0.f, s2 = 0.f;
    for (int i = 0; i < nb; ++i) {
        s  += part[(c * nb + i) * 2 + 0];
        s2 += part[(c * nb + i) * 2 + 1];
    }
    float m = s * invHW;
    float var = s2 * invHW - m * m;
    if (var < 0.f) var = 0.f;
    stats[c * 2 + 0] = m;
    stats[c * 2 + 1] = rsqrtf(var + 1e-6f);
}

__global__ __launch_bounds__(256) void ln_apply_k(
    float* __restrict__ buf, const float* __restrict__ stats,
    const float* __restrict__ g, const float* __restrict__ b, int HW) {
    int i = blockIdx.x * 256 + threadIdx.x;
    int c = i / HW;      // HW is a power of two
    int hw = i % HW;
    float m = stats[c * 2], inv = stats[c * 2 + 1];
    float x = buf[i];
    float r = fmaf((x - m) * inv, g[hw], b[hw]);
    buf[i] = fmaxf(r, 0.f);
}

// ---------------- adaptive 3x3 avg pool -> gf_cat[c][colOff + bin] ----------------
__global__ __launch_bounds__(256) void apool3_k(const float* __restrict__ in,
                                                float* __restrict__ gfc,
                                                int H, int W, int colOff) {
    int c = (int)blockIdx.x / 9;
    int bin = (int)blockIdx.x % 9;
    int bh = bin / 3, bw = bin % 3;
    int hs = bh * H / 3, he = ((bh + 1) * H + 2) / 3;
    int wsx = bw * W / 3, we = ((bw + 1) * W + 2) / 3;
    int rw = we - wsx, rh = he - hs, n = rw * rh;
    const float* b = in + c * H * W;
    float s = 0.f;
    for (int t = threadIdx.x; t < n; t += 256) {
        int iy = t / rw, ix = t % rw;
        s += b[(hs + iy) * W + (wsx + ix)];
    }
    __shared__ float rs[256];
    rs[threadIdx.x] = s;
    __syncthreads();
    for (int st = 128; st > 0; st >>= 1) {
        if (threadIdx.x < st) rs[threadIdx.x] += rs[threadIdx.x + st];
        __syncthreads();
    }
    if (threadIdx.x == 0) gfc[c * 18 + colOff + bin] = rs[0] / (float)n;
}

// ---------------- conv1d (42->779) + LN(18) + relu ----------------
__global__ __launch_bounds__(64) void gt1_k(const float* __restrict__ gfc,
                                            const float* __restrict__ w,
                                            const float* __restrict__ g,
                                            const float* __restrict__ b,
                                            float* __restrict__ outh) {
    int o = blockIdx.x;     // 779
    int p = threadIdx.x;
    __shared__ float vals[18];
    if (p < 18) {
        float acc = 0.f;
        const float* wo = w + o * 42 * 3;
        for (int c = 0; c < 42; ++c) {
            const float* gr = gfc + c * 18;
            #pragma unroll
            for (int k = 0; k < 3; ++k) {
                int pk = p + k - 1;
                if (pk >= 0 && pk < 18) acc = fmaf(wo[c * 3 + k], gr[pk], acc);
            }
        }
        vals[p] = acc;
    }
    __syncthreads();
    if (p < 18) {
        float s = 0.f, s2 = 0.f;
        #pragma unroll
        for (int j = 0; j < 18; ++j) { float x = vals[j]; s += x; s2 += x * x; }
        float m = s / 18.f;
        float var = s2 / 18.f - m * m;
        if (var < 0.f) var = 0.f;
        float inv = rsqrtf(var + 1e-6f);
        float r = fmaf((vals[p] - m) * inv, g[p], b[p]);
        outh[o * 18 + p] = fmaxf(r, 0.f);
    }
}

// ---------------- conv1d (779->1558) + LN(18) + relu -> vf cols 11..28 ----------------
__global__ __launch_bounds__(64) void gt2_k(const float* __restrict__ h,
                                            const float* __restrict__ w,
                                            const float* __restrict__ g,
                                            const float* __restrict__ b,
                                            float* __restrict__ vf) {
    int o = blockIdx.x;     // 1558
    int lane = threadIdx.x;
    float part[18];
    #pragma unroll
    for (int p = 0; p < 18; ++p) part[p] = 0.f;
    for (int c = lane; c < HALF_V; c += 64) {
        const float* wr = w + (o * HALF_V + c) * 3;
        float w0 = wr[0], w1 = wr[1], w2 = wr[2];
        const float* hr = h + c * 18;
        float hv[18];
        #pragma unroll
        for (int p = 0; p < 18; ++p) hv[p] = hr[p];
        #pragma unroll
        for (int p = 0; p < 18; ++p) {
            float a = w1 * hv[p];
            if (p > 0)  a = fmaf(w0, hv[p - 1], a);
            if (p < 17) a = fmaf(w2, hv[p + 1], a);
            part[p] += a;
        }
    }
    #pragma unroll
    for (int p = 0; p < 18; ++p) {
        float vv = part[p];
        for (int off = 32; off > 0; off >>= 1) vv += __shfl_xor(vv, off, 64);
        part[p] = vv;
    }
    float s = 0.f, s2 = 0.f;
    #pragma unroll
    for (int p = 0; p < 18; ++p) { s += part[p]; s2 += part[p] * part[p]; }
    float m = s / 18.f;
    float var = s2 / 18.f - m * m;
    if (var < 0.f) var = 0.f;
    float inv = rsqrtf(var + 1e-6f);
    if (lane < 18) {
        float r = fmaf((part[lane] - m) * inv, g[lane], b[lane]);
        vf[o * 32 + 11 + lane] = fmaxf(r, 0.f);
    }
}

// ---------------- argmin: one wave per query ----------------
__global__ __launch_bounds__(256) void argmin_k(
    const float* __restrict__ v, const float* __restrict__ vert,
    int* __restrict__ idx) {
    __shared__ float4 sv[NV_];
    int tid = threadIdx.x;
    for (int i = tid; i < NV_; i += 256) {
        float x = vert[i * 3 + 0], y = vert[i * 3 + 1], z = vert[i * 3 + 2];
        float pn = __fadd_rn(__fadd_rn(__fmul_rn(x, x), __fmul_rn(y, y)), __fmul_rn(z, z));
        sv[i] = make_float4(x, y, z, pn);
    }
    __syncthreads();
    int lane = tid & 63;
    int q = blockIdx.x * 4 + (tid >> 6);
    float vx = v[q * 3 + 0], vy = v[q * 3 + 1], vz = v[q * 3 + 2];
    float vn = __fadd_rn(__fadd_rn(__fmul_rn(vx, vx), __fmul_rn(vy, vy)), __fmul_rn(vz, vz));
    float best = 3.4e38f;
    int bi = 0;
    // d2 = (|v|^2 + |p|^2) - 2*(v.p), np-rounding preserved (no fma contraction)
    for (int p = lane; p < NV_; p += 64) {
        float4 pv = sv[p];
        float dot = __fadd_rn(__fadd_rn(__fmul_rn(vx, pv.x), __fmul_rn(vy, pv.y)), __fmul_rn(vz, pv.z));
        float d2 = __fsub_rn(__fadd_rn(vn, pv.w), __fmul_rn(2.f, dot));
        if (d2 < best) { best = d2; bi = p; }   // ascending p => keeps smallest idx on ties
    }
    #pragma unroll
    for (int off = 1; off < 64; off <<= 1) {
        float od = __shfl_xor(best, off, 64);
        int   oi = __shfl_xor(bi, off, 64);
        if (od < best || (od == best && oi < bi)) { best = od; bi = oi; }
    }
    if (lane == 0) idx[q] = bi;
}

// ---------------- MLP: 4 lanes per query, weights in LDS ----------------
__global__ __launch_bounds__(256) void mlp_k(
    const int* __restrict__ idx,
    const float* __restrict__ vvis, const float* __restrict__ qvis,
    const float* __restrict__ ixy, const float* __restrict__ fxy,
    const float* __restrict__ lat, const float* __restrict__ vf,
    const float* __restrict__ atw1, const float* __restrict__ atw2,
    const float* __restrict__ fcw1, const float* __restrict__ fcw2,
    float* __restrict__ out) {
    __shared__ float wbuf[96 * 96];     // 36.0 KB (atw1 -> fcw1 -> fcw2^T)
    __shared__ float w2buf[6 * 96];     //  2.25 KB
    __shared__ float yv[QPB * YVS];     // 25.0 KB
    int t = threadIdx.x;
    // stage atw1 + atw2
    {
        const float4* s = (const float4*)atw1;
        float4* d = (float4*)wbuf;
        for (int i = t; i < 96 * 96 / 4; i += 256) d[i] = s[i];
        const float4* s2 = (const float4*)atw2;
        float4* d2 = (float4*)w2buf;
        for (int i = t; i < 6 * 96 / 4; i += 256) d2[i] = s2[i];
    }
    int ql = t >> 2, part = t & 3;
    int q = blockIdx.x * QPB + ql;
    int bi = idx[q];
    int bi2 = bi + HALF_V; if (bi2 >= NV_) bi2 -= NV_;
    const float* f  = vf + bi * 32;
    const float* ft = vf + bi2 * 32;
    float vis = vvis[bi], vist = vvis[bi2];
    float* myv = &yv[ql * YVS];
    // build this lane's 24 yv entries
    for (int jj = 0; jj < 24; ++jj) {
        int j = part * 24 + jj;
        float val;
        if (j < 3)       val = ixy[q * 3 + j];
        else if (j < 11) val = fxy[q * 8 + j - 3];
        else if (j < 22) val = f[j - 11] * vis;
        else if (j < 33) val = ft[j - 22] * vist;
        else if (j < 51) val = f[11 + j - 33] * vis;
        else if (j < 69) val = ft[11 + j - 51] * vist;
        else if (j < 93) val = lat[q * 24 + j - 69];
        else if (j == 93) val = qvis[q];
        else if (j == 94) val = vis;
        else              val = vist;
        myv[j] = val;
    }
    __syncthreads();
    // layer 1: h[part*24 .. part*24+24) = relu(atw1 . yv)
    float h[24];
    #pragma unroll
    for (int r = 0; r < 24; ++r) h[r] = 0.f;
    {
        const float* wrow = &wbuf[part * 24 * 96];
        for (int c = 0; c < 96; c += 4) {
            float4 y4 = *(const float4*)&myv[c];
            #pragma unroll
            for (int r = 0; r < 24; ++r) {
                float4 w4 = *(const float4*)&wrow[r * 96 + c];
                h[r] = fmaf(w4.x, y4.x, h[r]);
                h[r] = fmaf(w4.y, y4.y, h[r]);
                h[r] = fmaf(w4.z, y4.z, h[r]);
                h[r] = fmaf(w4.w, y4.w, h[r]);
            }
        }
    }
    #pragma unroll
    for (int r = 0; r < 24; ++r) h[r] = fmaxf(h[r], 0.f);
    // at6 = sigmoid(atw2 . h): partial over this lane's 24 channels, quad-reduce
    float a6[6];
    #pragma unroll
    for (int o = 0; o < 6; ++o) a6[o] = 0.f;
    #pragma unroll
    for (int r = 0; r < 24; ++r) {
        float hv = h[r];
        #pragma unroll
        for (int o = 0; o < 6; ++o)
            a6[o] = fmaf(w2buf[o * 96 + part * 24 + r], hv, a6[o]);
    }
    #pragma unroll
    for (int o = 0; o < 6; ++o) {
        a6[o] += __shfl_xor(a6[o], 1, 64);
        a6[o] += __shfl_xor(a6[o], 2, 64);
        a6[o] = 1.f / (1.f + expf(-a6[o]));
    }
    // scale yv in place
    for (int jj = 0; jj < 24; ++jj) {
        int j = part * 24 + jj;
        float s;
        if (j < 11)      s = a6[0];
        else if (j < 22) s = a6[1];
        else if (j < 33) s = a6[2];
        else if (j < 51) s = a6[3];
        else if (j < 69) s = a6[4];
        else if (j < 93) s = a6[5];
        else             s = 1.f;
        myv[j] *= s;
    }
    __syncthreads();
    // restage fcw1
    {
        const float4* s = (const float4*)fcw1;
        float4* d = (float4*)wbuf;
        for (int i = t; i < 96 * 96 / 4; i += 256) d[i] = s[i];
    }
    __syncthreads();
    float h2[24];
    #pragma unroll
    for (int r = 0; r < 24; ++r) h2[r] = 0.f;
    {
        const float* wrow = &wbuf[part * 24 * 96];
        for (int c = 0; c < 96; c += 4) {
            float4 y4 = *(const float4*)&myv[c];
            #pragma unroll
            for (int r = 0; r < 24; ++r) {
                float4 w4 = *(const float4*)&wrow[r * 96 + c];
                h2[r] = fmaf(w4.x, y4.x, h2[r]);
                h2[r] = fmaf(w4.y, y4.y, h2[r]);
                h2[r] = fmaf(w4.z, y4.z, h2[r]);
                h2[r] = fmaf(w4.w, y4.w, h2[r]);
            }
        }
    }
    #pragma unroll
    for (int r = 0; r < 24; ++r) h2[r] = fmaxf(h2[r], 0.f);
    __syncthreads();
    // stage fcw2 transposed: wT[c*40+o] = fcw2[o*96+c]
    for (int i = t; i < 40 * 96; i += 256) {
        int o = i / 96, c = i % 96;
        wbuf[c * 40 + o] = fcw2[i];
    }
    __syncthreads();
    float acc[40];
    #pragma unroll
    for (int o = 0; o < 40; ++o) acc[o] = 0.f;
    #pragma unroll
    for (int r = 0; r < 24; ++r) {
        float hv = h2[r];
        const float* wr = &wbuf[(part * 24 + r) * 40];
        #pragma unroll
        for (int o = 0; o < 40; o += 4) {
            float4 w4 = *(const float4*)&wr[o];
            acc[o + 0] = fmaf(w4.x, hv, acc[o + 0]);
            acc[o + 1] = fmaf(w4.y, hv, acc[o + 1]);
            acc[o + 2] = fmaf(w4.z, hv, acc[o + 2]);
            acc[o + 3] = fmaf(w4.w, hv, acc[o + 3]);
        }
    }
    #pragma unroll
    for (int o = 0; o < 40; ++o) {
        acc[o] += __shfl_xor(acc[o], 1, 64);
        acc[o] += __shfl_xor(acc[o], 2, 64);
    }
    float* op = out + q * 40 + part * 10;
    #pragma unroll
    for (int j = 0; j < 10; ++j) op[j] = acc[part * 10 + j];
}

extern "C" void kernel_launch(void* const* d_in, const int* in_sizes, int n_in,
                              void* d_out, int out_size, void* d_ws, size_t ws_size,
                              hipStream_t stream) {
    const float* vert_xy = (const float*)d_in[0];
    const float* ft1     = (const float*)d_in[1];
    const float* ft_xy   = (const float*)d_in[2];
    const float* vert    = (const float*)d_in[3];
    const float* v       = (const float*)d_in[4];
    const float* vvis    = (const float*)d_in[5];
    const float* qvis    = (const float*)d_in[6];
    const float* ixy     = (const float*)d_in[7];
    const float* img     = (const float*)d_in[8];
    const float* lat     = (const float*)d_in[9];
    const float* fcw1    = (const float*)d_in[10];
    const float* fcw2    = (const float*)d_in[11];
    const float* atw1    = (const float*)d_in[12];
    const float* atw2    = (const float*)d_in[13];
    const float* gtw1    = (const float*)d_in[14];
    const float* gtg1    = (const float*)d_in[15];
    const float* gtb1    = (const float*)d_in[16];
    const float* gtw2    = (const float*)d_in[17];
    const float* gtg2    = (const float*)d_in[18];
    const float* gtb2    = (const float*)d_in[19];
    const float* c3w1    = (const float*)d_in[20];
    const float* c3g1    = (const float*)d_in[21];
    const float* c3b1    = (const float*)d_in[22];
    const float* c3w2    = (const float*)d_in[23];
    const float* c3g2    = (const float*)d_in[24];
    const float* c3b2    = (const float*)d_in[25];
    const float* c4w1    = (const float*)d_in[26];
    const float* c4g1    = (const float*)d_in[27];
    const float* c4b1    = (const float*)d_in[28];
    const float* c4w2    = (const float*)d_in[29];
    const float* c4g2    = (const float*)d_in[30];
    const float* c4b2    = (const float*)d_in[31];
    float* out = (float*)d_out;
    float* ws  = (float*)d_ws;
    float* stats = ws + WS_STATS;
    float* gfc   = ws + WS_GFC;
    float* gth   = ws + WS_GTH;
    float* vfb   = ws + WS_VF;
    float* c3a   = ws + WS_C3A;
    float* c3bb  = ws + WS_C3B;
    float* c4a   = ws + WS_C4A;
    float* c4bb  = ws + WS_C4B;
    float* part_c3 = ws + WS_C4A;   // c4a not live during c3 chain
    float* part_c4 = ws + WS_C3A;   // c3a dead after c3 conv2
    int*   idx   = (int*)(ws + WS_C4B);  // c4bb dead after apool(c4)

    feat_sample_k<<<25, 64, 0, stream>>>(vert_xy, img, ft1, vfb);

    // c3 chain: ft1 (8,64,64) -> (21) -> (42) -> pool -> gfc cols 9..17
    conv2d_stats_k<<<21 * 16, 256, 0, stream>>>(ft1, c3w1, c3a, part_c3, 8, 64, 64, 16);
    ln_finalize_k<<<1, 64, 0, stream>>>(part_c3, stats + 0, 21, 16, 1.f / 4096.f);
    ln_apply_k<<<21 * 16, 256, 0, stream>>>(c3a, stats + 0, c3g1, c3b1, 4096);
    conv2d_stats_k<<<42 * 16, 256, 0, stream>>>(c3a, c3w2, c3bb, part_c3, 21, 64, 64, 16);
    ln_finalize_k<<<1, 64, 0, stream>>>(part_c3, stats + 128, 42, 16, 1.f / 4096.f);
    ln_apply_k<<<42 * 16, 256, 0, stream>>>(c3bb, stats + 128, c3g2, c3b2, 4096);
    apool3_k<<<42 * 9, 256, 0, stream>>>(c3bb, gfc, 64, 64, 9);

    // c4 chain: img (3,256,256) -> (21) -> (42) -> pool -> gfc cols 0..8
    conv2d_stats_k<<<21 * 256, 256, 0, stream>>>(img, c4w1, c4a, part_c4, 3, 256, 256, 256);
    ln_finalize_k<<<1, 64, 0, stream>>>(part_c4, stats + 256, 21, 256, 1.f / 65536.f);
    ln_apply_k<<<21 * 256, 256, 0, stream>>>(c4a, stats + 256, c4g1, c4b1, 65536);
    conv2d_stats_k<<<42 * 256, 256, 0, stream>>>(c4a, c4w2, c4bb, part_c4, 21, 256, 256, 256);
    ln_finalize_k<<<1, 64, 0, stream>>>(part_c4, stats + 384, 42, 256, 1.f / 65536.f);
    ln_apply_k<<<42 * 256, 256, 0, stream>>>(c4bb, stats + 384, c4g2, c4b2, 65536);
    apool3_k<<<42 * 9, 256, 0, stream>>>(c4bb, gfc, 256, 256, 0);

    // argmin AFTER apool(c4): idx[] overlaps the now-dead c4bb region
    argmin_k<<<NQ_ / 4, 256, 0, stream>>>(v, vert, idx);

    // global-token conv1d stack -> vf cols 11..28
    gt1_k<<<779, 64, 0, stream>>>(gfc, gtw1, gtg1, gtb1, gth);
    gt2_k<<<1558, 64, 0, stream>>>(gth, gtw2, gtg2, gtb2, vfb);

    // fused per-query MLP path
    mlp_k<<<NQ_ / QPB, 256, 0, stream>>>(idx, vvis, qvis, ixy, ft_xy, lat, vfb,
                                         atw1, atw2, fcw1, fcw2, out);
}

// Round 3
// 436.788 us; speedup vs baseline: 1.8320x; 1.5461x over previous
//
#include <hip/hip_runtime.h>
#include <hip/hip_bf16.h>
#include <math.h>

#define NQ_    65536
#define NV_    1558
#define HALF_V 779

// ws layout in floats (total 4,452,352 floats = 17.8 MB, same as round 1)
#define WS_STATS 0          //   512
#define WS_GFC   512        //   768
#define WS_GTH   1280       // 14080
#define WS_VF    15360      // 50176 (1558*32)
#define WS_C3A   65536      // 86016  (reused: bf16 weights after c3 conv2)
#define WS_C3B   151552     // 172032 (tail reused for c4 stat partials)
#define WS_C4A   323584     // 1376256 (head reused for c3 stat partials)
#define WS_C4B   1699840    // 2752512 (reused for idx[] after apool(c4))

typedef __attribute__((ext_vector_type(8))) short bf16x8;
typedef __attribute__((ext_vector_type(4))) float f32x4;

__device__ __forceinline__ short f2b(float x) {
    union { __hip_bfloat16 h; short s; } u; u.h = __float2bfloat16(x); return u.s;
}
__device__ __forceinline__ float b2f(short s) {
    union { __hip_bfloat16 h; short s; } u; u.s = s; return __bfloat162float(u.h);
}

// ---------------- bilinear feature sampling (vertices) ----------------
__device__ __forceinline__ void bsample(const float* __restrict__ f, int C, int H, int W,
                                        float xn, float yn, float* __restrict__ o) {
    float x = (xn + 1.f) * 0.5f * (float)(W - 1);
    float y = (yn + 1.f) * 0.5f * (float)(H - 1);
    float x0f = floorf(x), y0f = floorf(y);
    float wx = x - x0f, wy = y - y0f;
    int x0 = (int)fminf(fmaxf(x0f, 0.f), (float)(W - 1));
    int x1 = (int)fminf(fmaxf(x0f + 1.f, 0.f), (float)(W - 1));
    int y0 = (int)fminf(fmaxf(y0f, 0.f), (float)(H - 1));
    int y1 = (int)fminf(fmaxf(y0f + 1.f, 0.f), (float)(H - 1));
    for (int c = 0; c < C; ++c) {
        const float* b = f + c * H * W;
        float v00 = b[y0 * W + x0], v01 = b[y0 * W + x1];
        float v10 = b[y1 * W + x0], v11 = b[y1 * W + x1];
        o[c] = v00 * (1.f - wx) * (1.f - wy) + v01 * wx * (1.f - wy)
             + v10 * (1.f - wx) * wy       + v11 * wx * wy;
    }
}

__global__ void feat_sample_k(const float* __restrict__ vert_xy,
                              const float* __restrict__ img,
                              const float* __restrict__ ft1,
                              float* __restrict__ vf) {
    int v = blockIdx.x * 64 + threadIdx.x;
    if (v >= NV_) return;
    float xn = vert_xy[v * 2 + 0], yn = vert_xy[v * 2 + 1];
    float tmp[8];
    bsample(img, 3, 256, 256, xn, yn, tmp);
    float* o = vf + v * 32;
    o[0] = tmp[0]; o[1] = tmp[1]; o[2] = tmp[2];
    bsample(ft1, 8, 64, 64, xn, yn, tmp);
    #pragma unroll
    for (int c = 0; c < 8; ++c) o[3 + c] = tmp[c];
}

// ---------------- conv2d 3x3 pad1, CB output channels per thread ----------------
template <int CB>
__global__ __launch_bounds__(256) void conv_k(
    const float* __restrict__ in, const float* __restrict__ w,
    float* __restrict__ out, int Cin, int H, int W) {
    int c0 = blockIdx.y * CB;
    int pix = blockIdx.x * 256 + threadIdx.x;
    int HW = H * W;
    int y = pix / W, x = pix % W;
    float acc[CB];
    #pragma unroll
    for (int j = 0; j < CB; ++j) acc[j] = 0.f;
    for (int ci = 0; ci < Cin; ++ci) {
        const float* ip = in + ci * HW;
        const float* wp = w + (c0 * Cin + ci) * 9;   // row j at + j*Cin*9
        #pragma unroll
        for (int dy = 0; dy < 3; ++dy) {
            int yy = y + dy - 1;
            if (yy < 0 || yy >= H) continue;
            #pragma unroll
            for (int dx = 0; dx < 3; ++dx) {
                int xx = x + dx - 1;
                if (xx < 0 || xx >= W) continue;
                float v = ip[yy * W + xx];
                #pragma unroll
                for (int j = 0; j < CB; ++j)
                    acc[j] = fmaf(wp[j * Cin * 9 + dy * 3 + dx], v, acc[j]);
            }
        }
    }
    #pragma unroll
    for (int j = 0; j < CB; ++j) out[(c0 + j) * HW + pix] = acc[j];
}

// ---------------- per-channel sum/sumsq partials over HW ----------------
__global__ __launch_bounds__(256) void stats_k(const float* __restrict__ buf,
                                               float* __restrict__ part,
                                               int HW, int nb) {
    int c = blockIdx.y, b = blockIdx.x;
    const float* p = buf + c * HW;
    float s = 0.f, s2 = 0.f;
    for (int i = b * 256 + threadIdx.x; i < HW; i += nb * 256) {
        float x = p[i]; s += x; s2 += x * x;
    }
    __shared__ float rs[256], rq[256];
    rs[threadIdx.x] = s; rq[threadIdx.x] = s2;
    __syncthreads();
    for (int st = 128; st > 0; st >>= 1) {
        if (threadIdx.x < st) { rs[threadIdx.x] += rs[threadIdx.x + st]; rq[threadIdx.x] += rq[threadIdx.x + st]; }
        __syncthreads();
    }
    if (threadIdx.x == 0) {
        part[(c * nb + b) * 2 + 0] = rs[0];
        part[(c * nb + b) * 2 + 1] = rq[0];
    }
}

__global__ void ln_finalize_k(const float* __restrict__ part, float* __restrict__ stats,
                              int C, int nb, float invHW) {
    int c = threadIdx.x;
    if (c >= C) return;
    float s = 0.f, s2 = 0.f;
    for (int i = 0; i < nb; ++i) {
        s  += part[(c * nb + i) * 2 + 0];
        s2 += part[(c * nb + i) * 2 + 1];
    }
    float m = s * invHW;
    float var = s2 * invHW - m * m;
    if (var < 0.f) var = 0.f;
    stats[c * 2 + 0] = m;
    stats[c * 2 + 1] = rsqrtf(var + 1e-6f);
}

__global__ __launch_bounds__(256) void ln_apply_k(
    float* __restrict__ buf, const float* __restrict__ stats,
    const float* __restrict__ g, const float* __restrict__ b, int HW) {
    int i = blockIdx.x * 256 + threadIdx.x;
    int c = i / HW;      // HW is a power of two
    int hw = i % HW;
    float m = stats[c * 2], inv = stats[c * 2 + 1];
    float x = buf[i];
    float r = fmaf((x - m) * inv, g[hw], b[hw]);
    buf[i] = fmaxf(r, 0.f);
}

// ---------------- adaptive 3x3 avg pool -> gf_cat[c][colOff + bin] ----------------
__global__ __launch_bounds__(256) void apool3_k(const float* __restrict__ in,
                                                float* __restrict__ gfc,
                                                int H, int W, int colOff) {
    int c = (int)blockIdx.x / 9;
    int bin = (int)blockIdx.x % 9;
    int bh = bin / 3, bw = bin % 3;
    int hs = bh * H / 3, he = ((bh + 1) * H + 2) / 3;
    int wsx = bw * W / 3, we = ((bw + 1) * W + 2) / 3;
    int rw = we - wsx, rh = he - hs, n = rw * rh;
    const float* b = in + c * H * W;
    float s = 0.f;
    for (int t = threadIdx.x; t < n; t += 256) {
        int iy = t / rw, ix = t % rw;
        s += b[(hs + iy) * W + (wsx + ix)];
    }
    __shared__ float rs[256];
    rs[threadIdx.x] = s;
    __syncthreads();
    for (int st = 128; st > 0; st >>= 1) {
        if (threadIdx.x < st) rs[threadIdx.x] += rs[threadIdx.x + st];
        __syncthreads();
    }
    if (threadIdx.x == 0) gfc[c * 18 + colOff + bin] = rs[0] / (float)n;
}

// ---------------- conv1d (42->779) + LN(18) + relu ----------------
__global__ __launch_bounds__(64) void gt1_k(const float* __restrict__ gfc,
                                            const float* __restrict__ w,
                                            const float* __restrict__ g,
                                            const float* __restrict__ b,
                                            float* __restrict__ outh) {
    int o = blockIdx.x;     // 779
    int p = threadIdx.x;
    __shared__ float vals[18];
    if (p < 18) {
        float acc = 0.f;
        const float* wo = w + o * 42 * 3;
        for (int c = 0; c < 42; ++c) {
            const float* gr = gfc + c * 18;
            #pragma unroll
            for (int k = 0; k < 3; ++k) {
                int pk = p + k - 1;
                if (pk >= 0 && pk < 18) acc = fmaf(wo[c * 3 + k], gr[pk], acc);
            }
        }
        vals[p] = acc;
    }
    __syncthreads();
    if (p < 18) {
        float s = 0.f, s2 = 0.f;
        #pragma unroll
        for (int j = 0; j < 18; ++j) { float x = vals[j]; s += x; s2 += x * x; }
        float m = s / 18.f;
        float var = s2 / 18.f - m * m;
        if (var < 0.f) var = 0.f;
        float inv = rsqrtf(var + 1e-6f);
        float r = fmaf((vals[p] - m) * inv, g[p], b[p]);
        outh[o * 18 + p] = fmaxf(r, 0.f);
    }
}

// ---------------- conv1d (779->1558) + LN(18) + relu -> vf cols 11..28 ----------------
__global__ __launch_bounds__(64) void gt2_k(const float* __restrict__ h,
                                            const float* __restrict__ w,
                                            const float* __restrict__ g,
                                            const float* __restrict__ b,
                                            float* __restrict__ vf) {
    int o = blockIdx.x;     // 1558
    int lane = threadIdx.x;
    float part[18];
    #pragma unroll
    for (int p = 0; p < 18; ++p) part[p] = 0.f;
    for (int c = lane; c < HALF_V; c += 64) {
        const float* wr = w + (o * HALF_V + c) * 3;
        float w0 = wr[0], w1 = wr[1], w2 = wr[2];
        const float* hr = h + c * 18;
        float hv[18];
        #pragma unroll
        for (int p = 0; p < 18; ++p) hv[p] = hr[p];
        #pragma unroll
        for (int p = 0; p < 18; ++p) {
            float a = w1 * hv[p];
            if (p > 0)  a = fmaf(w0, hv[p - 1], a);
            if (p < 17) a = fmaf(w2, hv[p + 1], a);
            part[p] += a;
        }
    }
    #pragma unroll
    for (int p = 0; p < 18; ++p) {
        float vv = part[p];
        for (int off = 32; off > 0; off >>= 1) vv += __shfl_xor(vv, off, 64);
        part[p] = vv;
    }
    float s = 0.f, s2 = 0.f;
    #pragma unroll
    for (int p = 0; p < 18; ++p) { s += part[p]; s2 += part[p] * part[p]; }
    float m = s / 18.f;
    float var = s2 / 18.f - m * m;
    if (var < 0.f) var = 0.f;
    float inv = rsqrtf(var + 1e-6f);
    if (lane < 18) {
        float r = fmaf((part[lane] - m) * inv, g[lane], b[lane]);
        vf[o * 32 + 11 + lane] = fmaxf(r, 0.f);
    }
}

// ---------------- argmin: one wave per query ----------------
__global__ __launch_bounds__(256) void argmin_k(
    const float* __restrict__ v, const float* __restrict__ vert,
    int* __restrict__ idx) {
    __shared__ float4 sv[NV_];
    int tid = threadIdx.x;
    for (int i = tid; i < NV_; i += 256) {
        float x = vert[i * 3 + 0], y = vert[i * 3 + 1], z = vert[i * 3 + 2];
        float pn = __fadd_rn(__fadd_rn(__fmul_rn(x, x), __fmul_rn(y, y)), __fmul_rn(z, z));
        sv[i] = make_float4(x, y, z, pn);
    }
    __syncthreads();
    int lane = tid & 63;
    int q = blockIdx.x * 4 + (tid >> 6);
    float vx = v[q * 3 + 0], vy = v[q * 3 + 1], vz = v[q * 3 + 2];
    float vn = __fadd_rn(__fadd_rn(__fmul_rn(vx, vx), __fmul_rn(vy, vy)), __fmul_rn(vz, vz));
    float best = 3.4e38f;
    int bi = 0;
    // d2 = (|v|^2 + |p|^2) - 2*(v.p), np-rounding preserved (no fma contraction)
    for (int p = lane; p < NV_; p += 64) {
        float4 pv = sv[p];
        float dot = __fadd_rn(__fadd_rn(__fmul_rn(vx, pv.x), __fmul_rn(vy, pv.y)), __fmul_rn(vz, pv.z));
        float d2 = __fsub_rn(__fadd_rn(vn, pv.w), __fmul_rn(2.f, dot));
        if (d2 < best) { best = d2; bi = p; }   // ascending p => keeps smallest idx on ties
    }
    #pragma unroll
    for (int off = 1; off < 64; off <<= 1) {
        float od = __shfl_xor(best, off, 64);
        int   oi = __shfl_xor(bi, off, 64);
        if (od < best || (od == best && oi < bi)) { best = od; bi = oi; }
    }
    if (lane == 0) idx[q] = bi;
}

// ---------------- weight f32 -> bf16 (with row zero-padding) ----------------
// wb layout (shorts): [0,9216) atw1 ; [9216,10752) atw2 pad to 16 rows ;
//                     [10752,19968) fcw1 ; [19968,24576) fcw2 pad to 48 rows
__global__ void wcvt_k(const float* __restrict__ atw1, const float* __restrict__ atw2,
                       const float* __restrict__ fcw1, const float* __restrict__ fcw2,
                       short* __restrict__ wb) {
    int i = blockIdx.x * 256 + threadIdx.x;   // grid 96 -> 24576
    short v = 0;
    if (i < 9216) v = f2b(atw1[i]);
    else if (i < 10752) { int j = i - 9216; v = (j < 576) ? f2b(atw2[j]) : (short)0; }
    else if (i < 19968) v = f2b(fcw1[i - 10752]);
    else { int j = i - 19968; v = (j < 3840) ? f2b(fcw2[j]) : (short)0; }
    wb[i] = v;
}

// ---------------- MFMA MLP: 16 queries per wave, 64 per block ----------------
#define YP 104   // padded LDS row stride in shorts (2-way bank aliasing only)

__global__ __launch_bounds__(256) void mlp_mfma_k(
    const int* __restrict__ idx,
    const float* __restrict__ vvis, const float* __restrict__ qvis,
    const float* __restrict__ ixy, const float* __restrict__ fxy,
    const float* __restrict__ lat, const float* __restrict__ vf,
    const short* __restrict__ wb, float* __restrict__ out) {
    __shared__ short Y[64 * YP];
    __shared__ short Hb[64 * YP];
    __shared__ float A6[64 * 8];
    int t = threadIdx.x;
    int lane = t & 63, wave = t >> 6;
    int q0 = blockIdx.x * 64;

    // ---- y build: 4 lanes per query, bf16 into LDS; keep f32 copy in regs ----
    int ql = t >> 2, part = t & 3;
    int q = q0 + ql;
    int bi = idx[q];
    int bi2 = bi + HALF_V; if (bi2 >= NV_) bi2 -= NV_;
    const float* f  = vf + bi * 32;
    const float* ft = vf + bi2 * 32;
    float vis = vvis[bi], vist = vvis[bi2];
    short* yr = &Y[ql * YP];
    float myv[24];
    #pragma unroll
    for (int jj = 0; jj < 24; ++jj) {
        int j = part * 24 + jj;
        float val;
        if (j < 3)       val = ixy[q * 3 + j];
        else if (j < 11) val = fxy[q * 8 + j - 3];
        else if (j < 22) val = f[j - 11] * vis;
        else if (j < 33) val = ft[j - 22] * vist;
        else if (j < 51) val = f[11 + j - 33] * vis;
        else if (j < 69) val = ft[11 + j - 51] * vist;
        else if (j < 93) val = lat[q * 24 + j - 69];
        else if (j == 93) val = qvis[q];
        else if (j == 94) val = vis;
        else              val = vist;
        myv[jj] = val;
        yr[j] = f2b(val);
    }
    __syncthreads();

    int nloc = lane & 15, quad = lane >> 4;
    const short* Ya = &Y[(wave * 16 + nloc) * YP];
    const short* Ha = &Hb[(wave * 16 + nloc) * YP];
    int hrow = wave * 16 + quad * 4;    // C-layout row base for this lane

    // ---- GEMM1: H = relu(Y x atw1^T) ----
    f32x4 acc[6];
    #pragma unroll
    for (int nt = 0; nt < 6; ++nt) acc[nt] = (f32x4){0.f, 0.f, 0.f, 0.f};
    #pragma unroll
    for (int k0 = 0; k0 < 96; k0 += 32) {
        bf16x8 a = *(const bf16x8*)(Ya + k0 + quad * 8);
        #pragma unroll
        for (int nt = 0; nt < 6; ++nt) {
            bf16x8 b = *(const bf16x8*)(wb + (nt * 16 + nloc) * 96 + k0 + quad * 8);
            acc[nt] = __builtin_amdgcn_mfma_f32_16x16x32_bf16(a, b, acc[nt], 0, 0, 0);
        }
    }
    #pragma unroll
    for (int nt = 0; nt < 6; ++nt)
        #pragma unroll
        for (int r = 0; r < 4; ++r)
            Hb[(hrow + r) * YP + nt * 16 + nloc] = f2b(fmaxf(acc[nt][r], 0.f));
    __syncthreads();

    // ---- GEMM2: at6 = sigmoid(H x atw2^T) ----
    {
        const short* w2 = wb + 9216;
        f32x4 a2 = (f32x4){0.f, 0.f, 0.f, 0.f};
        #pragma unroll
        for (int k0 = 0; k0 < 96; k0 += 32) {
            bf16x8 a = *(const bf16x8*)(Ha + k0 + quad * 8);
            bf16x8 b = *(const bf16x8*)(w2 + nloc * 96 + k0 + quad * 8);
            a2 = __builtin_amdgcn_mfma_f32_16x16x32_bf16(a, b, a2, 0, 0, 0);
        }
        if (nloc < 6) {
            #pragma unroll
            for (int r = 0; r < 4; ++r)
                A6[(hrow + r) * 8 + nloc] = 1.f / (1.f + expf(-a2[r]));
        }
    }
    __syncthreads();

    // ---- scale Y in place from f32 register copy ----
    {
        const float* ap = &A6[ql * 8];
        #pragma unroll
        for (int jj = 0; jj < 24; ++jj) {
            int j = part * 24 + jj;
            float s;
            if (j < 11)      s = ap[0];
            else if (j < 22) s = ap[1];
            else if (j < 33) s = ap[2];
            else if (j < 51) s = ap[3];
            else if (j < 69) s = ap[4];
            else if (j < 93) s = ap[5];
            else             s = 1.f;
            yr[j] = f2b(myv[jj] * s);
        }
    }
    __syncthreads();

    // ---- GEMM3: H2 = relu(Y2 x fcw1^T) ----
    {
        const short* w3 = wb + 10752;
        #pragma unroll
        for (int nt = 0; nt < 6; ++nt) acc[nt] = (f32x4){0.f, 0.f, 0.f, 0.f};
        #pragma unroll
        for (int k0 = 0; k0 < 96; k0 += 32) {
            bf16x8 a = *(const bf16x8*)(Ya + k0 + quad * 8);
            #pragma unroll
            for (int nt = 0; nt < 6; ++nt) {
                bf16x8 b = *(const bf16x8*)(w3 + (nt * 16 + nloc) * 96 + k0 + quad * 8);
                acc[nt] = __builtin_amdgcn_mfma_f32_16x16x32_bf16(a, b, acc[nt], 0, 0, 0);
            }
        }
        #pragma unroll
        for (int nt = 0; nt < 6; ++nt)
            #pragma unroll
            for (int r = 0; r < 4; ++r)
                Hb[(hrow + r) * YP + nt * 16 + nloc] = f2b(fmaxf(acc[nt][r], 0.f));
    }
    __syncthreads();

    // ---- GEMM4: OUT = H2 x fcw2^T ----
    {
        const short* w4 = wb + 19968;
        f32x4 oacc[3];
        #pragma unroll
        for (int nt = 0; nt < 3; ++nt) oacc[nt] = (f32x4){0.f, 0.f, 0.f, 0.f};
        #pragma unroll
        for (int k0 = 0; k0 < 96; k0 += 32) {
            bf16x8 a = *(const bf16x8*)(Ha + k0 + quad * 8);
            #pragma unroll
            for (int nt = 0; nt < 3; ++nt) {
                bf16x8 b = *(const bf16x8*)(w4 + (nt * 16 + nloc) * 96 + k0 + quad * 8);
                oacc[nt] = __builtin_amdgcn_mfma_f32_16x16x32_bf16(a, b, oacc[nt], 0, 0, 0);
            }
        }
        #pragma unroll
        for (int nt = 0; nt < 3; ++nt) {
            int oc = nt * 16 + nloc;
            if (oc < 40) {
                #pragma unroll
                for (int r = 0; r < 4; ++r)
                    out[(q0 + hrow + r) * 40 + oc] = oacc[nt][r];
            }
        }
    }
}

extern "C" void kernel_launch(void* const* d_in, const int* in_sizes, int n_in,
                              void* d_out, int out_size, void* d_ws, size_t ws_size,
                              hipStream_t stream) {
    const float* vert_xy = (const float*)d_in[0];
    const float* ft1     = (const float*)d_in[1];
    const float* ft_xy   = (const float*)d_in[2];
    const float* vert    = (const float*)d_in[3];
    const float* v       = (const float*)d_in[4];
    const float* vvis    = (const float*)d_in[5];
    const float* qvis    = (const float*)d_in[6];
    const float* ixy     = (const float*)d_in[7];
    const float* img     = (const float*)d_in[8];
    const float* lat     = (const float*)d_in[9];
    const float* fcw1    = (const float*)d_in[10];
    const float* fcw2    = (const float*)d_in[11];
    const float* atw1    = (const float*)d_in[12];
    const float* atw2    = (const float*)d_in[13];
    const float* gtw1    = (const float*)d_in[14];
    const float* gtg1    = (const float*)d_in[15];
    const float* gtb1    = (const float*)d_in[16];
    const float* gtw2    = (const float*)d_in[17];
    const float* gtg2    = (const float*)d_in[18];
    const float* gtb2    = (const float*)d_in[19];
    const float* c3w1    = (const float*)d_in[20];
    const float* c3g1    = (const float*)d_in[21];
    const float* c3b1    = (const float*)d_in[22];
    const float* c3w2    = (const float*)d_in[23];
    const float* c3g2    = (const float*)d_in[24];
    const float* c3b2    = (const float*)d_in[25];
    const float* c4w1    = (const float*)d_in[26];
    const float* c4g1    = (const float*)d_in[27];
    const float* c4b1    = (const float*)d_in[28];
    const float* c4w2    = (const float*)d_in[29];
    const float* c4g2    = (const float*)d_in[30];
    const float* c4b2    = (const float*)d_in[31];
    float* out = (float*)d_out;
    float* ws  = (float*)d_ws;
    float* stats = ws + WS_STATS;
    float* gfc   = ws + WS_GFC;
    float* gth   = ws + WS_GTH;
    float* vfb   = ws + WS_VF;
    float* c3a   = ws + WS_C3A;
    float* c3bb  = ws + WS_C3B;
    float* c4a   = ws + WS_C4A;
    float* c4bb  = ws + WS_C4B;
    float* part_c3 = ws + WS_C4A;            // c4a not live during c3 chain
    short* wbf     = (short*)(ws + WS_C3A);  // c3a dead after c3 conv2 (24576 shorts)
    float* part_c4 = ws + WS_C3B;            // c3bb dead after apool(c3)
    int*   idx   = (int*)(ws + WS_C4B);      // c4bb dead after apool(c4)

    feat_sample_k<<<25, 64, 0, stream>>>(vert_xy, img, ft1, vfb);

    // c3 chain: ft1 (8,64,64) -> (21) -> (42) -> pool -> gfc cols 9..17
    conv_k<7><<<dim3(16, 3), 256, 0, stream>>>(ft1, c3w1, c3a, 8, 64, 64);
    stats_k<<<dim3(4, 21), 256, 0, stream>>>(c3a, part_c3, 4096, 4);
    ln_finalize_k<<<1, 64, 0, stream>>>(part_c3, stats + 0, 21, 4, 1.f / 4096.f);
    ln_apply_k<<<21 * 16, 256, 0, stream>>>(c3a, stats + 0, c3g1, c3b1, 4096);
    conv_k<7><<<dim3(16, 6), 256, 0, stream>>>(c3a, c3w2, c3bb, 21, 64, 64);
    wcvt_k<<<96, 256, 0, stream>>>(atw1, atw2, fcw1, fcw2, wbf);  // c3a now dead
    stats_k<<<dim3(4, 42), 256, 0, stream>>>(c3bb, part_c3, 4096, 4);
    ln_finalize_k<<<1, 64, 0, stream>>>(part_c3, stats + 128, 42, 4, 1.f / 4096.f);
    ln_apply_k<<<42 * 16, 256, 0, stream>>>(c3bb, stats + 128, c3g2, c3b2, 4096);
    apool3_k<<<42 * 9, 256, 0, stream>>>(c3bb, gfc, 64, 64, 9);

    // c4 chain: img (3,256,256) -> (21) -> (42) -> pool -> gfc cols 0..8
    conv_k<7><<<dim3(256, 3), 256, 0, stream>>>(img, c4w1, c4a, 3, 256, 256);
    stats_k<<<dim3(32, 21), 256, 0, stream>>>(c4a, part_c4, 65536, 32);
    ln_finalize_k<<<1, 64, 0, stream>>>(part_c4, stats + 256, 21, 32, 1.f / 65536.f);
    ln_apply_k<<<21 * 256, 256, 0, stream>>>(c4a, stats + 256, c4g1, c4b1, 65536);
    conv_k<7><<<dim3(256, 6), 256, 0, stream>>>(c4a, c4w2, c4bb, 21, 256, 256);
    stats_k<<<dim3(32, 42), 256, 0, stream>>>(c4bb, part_c4, 65536, 32);
    ln_finalize_k<<<1, 64, 0, stream>>>(part_c4, stats + 384, 42, 32, 1.f / 65536.f);
    ln_apply_k<<<42 * 256, 256, 0, stream>>>(c4bb, stats + 384, c4g2, c4b2, 65536);
    apool3_k<<<42 * 9, 256, 0, stream>>>(c4bb, gfc, 256, 256, 0);

    // argmin AFTER apool(c4): idx[] overlaps the now-dead c4bb region
    argmin_k<<<NQ_ / 4, 256, 0, stream>>>(v, vert, idx);

    // global-token conv1d stack -> vf cols 11..28
    gt1_k<<<779, 64, 0, stream>>>(gfc, gtw1, gtg1, gtb1, gth);
    gt2_k<<<1558, 64, 0, stream>>>(gth, gtw2, gtg2, gtb2, vfb);

    // fused per-query MFMA MLP path
    mlp_mfma_k<<<NQ_ / 64, 256, 0, stream>>>(idx, vvis, qvis, ixy, ft_xy, lat, vfb,
                                             wbf, out);
}

// Round 4
// 404.303 us; speedup vs baseline: 1.9791x; 1.0803x over previous
//
#include <hip/hip_runtime.h>
#include <hip/hip_bf16.h>
#include <math.h>

#define NQ_    65536
#define NV_    1558
#define HALF_V 779

// ws layout in floats (total 4,452,352 floats = 17.8 MB)
#define WS_STATS 0          //   512
#define WS_GFC   512        //   768
#define WS_GTH   1280       // 14080
#define WS_VF    15360      // 50176 (1558*32)
#define WS_C3A   65536      // 86016  (reused: bf16 weights after c3 conv2)
#define WS_C3B   151552     // 172032 (tail reused for c4 stat partials)
#define WS_C4A   323584     // 1376256 (head reused for c3 stat partials)
#define WS_C4B   1699840    // 2752512 (reused for idx[] after apool(c4))

typedef __attribute__((ext_vector_type(8))) short bf16x8;
typedef __attribute__((ext_vector_type(4))) float f32x4;

__device__ __forceinline__ short f2b(float x) {
    union { __hip_bfloat16 h; short s; } u; u.h = __float2bfloat16(x); return u.s;
}

// ---------------- bilinear feature sampling (vertices) ----------------
__device__ __forceinline__ void bsample(const float* __restrict__ f, int C, int H, int W,
                                        float xn, float yn, float* __restrict__ o) {
    float x = (xn + 1.f) * 0.5f * (float)(W - 1);
    float y = (yn + 1.f) * 0.5f * (float)(H - 1);
    float x0f = floorf(x), y0f = floorf(y);
    float wx = x - x0f, wy = y - y0f;
    int x0 = (int)fminf(fmaxf(x0f, 0.f), (float)(W - 1));
    int x1 = (int)fminf(fmaxf(x0f + 1.f, 0.f), (float)(W - 1));
    int y0 = (int)fminf(fmaxf(y0f, 0.f), (float)(H - 1));
    int y1 = (int)fminf(fmaxf(y0f + 1.f, 0.f), (float)(H - 1));
    for (int c = 0; c < C; ++c) {
        const float* b = f + c * H * W;
        float v00 = b[y0 * W + x0], v01 = b[y0 * W + x1];
        float v10 = b[y1 * W + x0], v11 = b[y1 * W + x1];
        o[c] = v00 * (1.f - wx) * (1.f - wy) + v01 * wx * (1.f - wy)
             + v10 * (1.f - wx) * wy       + v11 * wx * wy;
    }
}

__global__ void feat_sample_k(const float* __restrict__ vert_xy,
                              const float* __restrict__ img,
                              const float* __restrict__ ft1,
                              float* __restrict__ vf) {
    int v = blockIdx.x * 64 + threadIdx.x;
    if (v >= NV_) return;
    float xn = vert_xy[v * 2 + 0], yn = vert_xy[v * 2 + 1];
    float tmp[8];
    bsample(img, 3, 256, 256, xn, yn, tmp);
    float* o = vf + v * 32;
    o[0] = tmp[0]; o[1] = tmp[1]; o[2] = tmp[2];
    bsample(ft1, 8, 64, 64, xn, yn, tmp);
    #pragma unroll
    for (int c = 0; c < 8; ++c) o[3 + c] = tmp[c];
}

// ---------------- conv2d 3x3 pad1: 2 pixels x CB channels per thread,
// ---------------- fused per-(channel,block) sum/sumsq partials ----------------
template <int CB>
__global__ __launch_bounds__(256) void conv2_k(
    const float* __restrict__ in, const float* __restrict__ w,
    float* __restrict__ out, float* __restrict__ part,
    int Cin, int H, int W) {
    int c0 = blockIdx.y * CB;
    int tid = threadIdx.x;
    int px0 = (blockIdx.x * 256 + tid) * 2;
    int HW = H * W;
    int y = px0 / W, x = px0 % W;      // x is even
    float acc0[CB], acc1[CB];
    #pragma unroll
    for (int j = 0; j < CB; ++j) { acc0[j] = 0.f; acc1[j] = 0.f; }
    const float* wbase = w + c0 * Cin * 9;
    #pragma unroll 2
    for (int ci = 0; ci < Cin; ++ci) {
        const float* ip = in + ci * HW;
        float win[3][4];
        #pragma unroll
        for (int r = 0; r < 3; ++r) {
            int yy = y + r - 1;
            bool okY = (yy >= 0) && (yy < H);
            const float* rp = ip + yy * W;
            float2 m = okY ? *(const float2*)(rp + x) : make_float2(0.f, 0.f);
            win[r][1] = m.x; win[r][2] = m.y;
            win[r][0] = (okY && x > 0)     ? rp[x - 1] : 0.f;
            win[r][3] = (okY && x + 2 < W) ? rp[x + 2] : 0.f;
        }
        const float* wc = wbase + ci * 9;
        #pragma unroll
        for (int j = 0; j < CB; ++j) {
            const float* wj = wc + j * Cin * 9;
            #pragma unroll
            for (int r = 0; r < 3; ++r) {
                float w0 = wj[r * 3 + 0], w1 = wj[r * 3 + 1], w2 = wj[r * 3 + 2];
                acc0[j] = fmaf(w0, win[r][0], fmaf(w1, win[r][1], fmaf(w2, win[r][2], acc0[j])));
                acc1[j] = fmaf(w0, win[r][1], fmaf(w1, win[r][2], fmaf(w2, win[r][3], acc1[j])));
            }
        }
    }
    #pragma unroll
    for (int j = 0; j < CB; ++j)
        *(float2*)(out + (c0 + j) * HW + px0) = make_float2(acc0[j], acc1[j]);

    // fused stats: per-(channel, block) sum / sumsq
    __shared__ float sred[4][CB][2];
    int lane = tid & 63, wave = tid >> 6;
    #pragma unroll
    for (int j = 0; j < CB; ++j) {
        float s = acc0[j] + acc1[j];
        float qq = acc0[j] * acc0[j] + acc1[j] * acc1[j];
        #pragma unroll
        for (int off = 1; off < 64; off <<= 1) {
            s  += __shfl_xor(s, off, 64);
            qq += __shfl_xor(qq, off, 64);
        }
        if (lane == 0) { sred[wave][j][0] = s; sred[wave][j][1] = qq; }
    }
    __syncthreads();
    if (tid < CB) {
        float s = sred[0][tid][0] + sred[1][tid][0] + sred[2][tid][0] + sred[3][tid][0];
        float qq = sred[0][tid][1] + sred[1][tid][1] + sred[2][tid][1] + sred[3][tid][1];
        int c = c0 + tid;
        part[(c * gridDim.x + blockIdx.x) * 2 + 0] = s;
        part[(c * gridDim.x + blockIdx.x) * 2 + 1] = qq;
    }
}

__global__ void ln_finalize_k(const float* __restrict__ part, float* __restrict__ stats,
                              int C, int nb, float invHW) {
    int c = threadIdx.x;
    if (c >= C) return;
    float s = 0.f, s2 = 0.f;
    for (int i = 0; i < nb; ++i) {
        s  += part[(c * nb + i) * 2 + 0];
        s2 += part[(c * nb + i) * 2 + 1];
    }
    float m = s * invHW;
    float var = s2 * invHW - m * m;
    if (var < 0.f) var = 0.f;
    stats[c * 2 + 0] = m;
    stats[c * 2 + 1] = rsqrtf(var + 1e-6f);
}

__global__ __launch_bounds__(256) void ln_apply_k(
    float* __restrict__ buf, const float* __restrict__ stats,
    const float* __restrict__ g, const float* __restrict__ b, int HW) {
    int i = blockIdx.x * 256 + threadIdx.x;
    int c = i / HW;      // HW is a power of two
    int hw = i % HW;
    float m = stats[c * 2], inv = stats[c * 2 + 1];
    float x = buf[i];
    float r = fmaf((x - m) * inv, g[hw], b[hw]);
    buf[i] = fmaxf(r, 0.f);
}

// ---------------- adaptive 3x3 avg pool -> gf_cat[c][colOff + bin] ----------------
__global__ __launch_bounds__(256) void apool3_k(const float* __restrict__ in,
                                                float* __restrict__ gfc,
                                                int H, int W, int colOff) {
    int c = (int)blockIdx.x / 9;
    int bin = (int)blockIdx.x % 9;
    int bh = bin / 3, bw = bin % 3;
    int hs = bh * H / 3, he = ((bh + 1) * H + 2) / 3;
    int wsx = bw * W / 3, we = ((bw + 1) * W + 2) / 3;
    int rw = we - wsx, rh = he - hs, n = rw * rh;
    const float* b = in + c * H * W;
    float s = 0.f;
    for (int t = threadIdx.x; t < n; t += 256) {
        int iy = t / rw, ix = t % rw;
        s += b[(hs + iy) * W + (wsx + ix)];
    }
    __shared__ float rs[256];
    rs[threadIdx.x] = s;
    __syncthreads();
    for (int st = 128; st > 0; st >>= 1) {
        if (threadIdx.x < st) rs[threadIdx.x] += rs[threadIdx.x + st];
        __syncthreads();
    }
    if (threadIdx.x == 0) gfc[c * 18 + colOff + bin] = rs[0] / (float)n;
}

// ---------------- conv1d (42->779) + LN(18) + relu ----------------
__global__ __launch_bounds__(64) void gt1_k(const float* __restrict__ gfc,
                                            const float* __restrict__ w,
                                            const float* __restrict__ g,
                                            const float* __restrict__ b,
                                            float* __restrict__ outh) {
    int o = blockIdx.x;     // 779
    int p = threadIdx.x;
    __shared__ float vals[18];
    if (p < 18) {
        float acc = 0.f;
        const float* wo = w + o * 42 * 3;
        for (int c = 0; c < 42; ++c) {
            const float* gr = gfc + c * 18;
            #pragma unroll
            for (int k = 0; k < 3; ++k) {
                int pk = p + k - 1;
                if (pk >= 0 && pk < 18) acc = fmaf(wo[c * 3 + k], gr[pk], acc);
            }
        }
        vals[p] = acc;
    }
    __syncthreads();
    if (p < 18) {
        float s = 0.f, s2 = 0.f;
        #pragma unroll
        for (int j = 0; j < 18; ++j) { float x = vals[j]; s += x; s2 += x * x; }
        float m = s / 18.f;
        float var = s2 / 18.f - m * m;
        if (var < 0.f) var = 0.f;
        float inv = rsqrtf(var + 1e-6f);
        float r = fmaf((vals[p] - m) * inv, g[p], b[p]);
        outh[o * 18 + p] = fmaxf(r, 0.f);
    }
}

// ---------------- conv1d (779->1558) + LN(18) + relu -> vf cols 11..28 ----------------
__global__ __launch_bounds__(64) void gt2_k(const float* __restrict__ h,
                                            const float* __restrict__ w,
                                            const float* __restrict__ g,
                                            const float* __restrict__ b,
                                            float* __restrict__ vf) {
    int o = blockIdx.x;     // 1558
    int lane = threadIdx.x;
    float part[18];
    #pragma unroll
    for (int p = 0; p < 18; ++p) part[p] = 0.f;
    for (int c = lane; c < HALF_V; c += 64) {
        const float* wr = w + (o * HALF_V + c) * 3;
        float w0 = wr[0], w1 = wr[1], w2 = wr[2];
        const float* hr = h + c * 18;
        float hv[18];
        #pragma unroll
        for (int p = 0; p < 18; ++p) hv[p] = hr[p];
        #pragma unroll
        for (int p = 0; p < 18; ++p) {
            float a = w1 * hv[p];
            if (p > 0)  a = fmaf(w0, hv[p - 1], a);
            if (p < 17) a = fmaf(w2, hv[p + 1], a);
            part[p] += a;
        }
    }
    #pragma unroll
    for (int p = 0; p < 18; ++p) {
        float vv = part[p];
        for (int off = 32; off > 0; off >>= 1) vv += __shfl_xor(vv, off, 64);
        part[p] = vv;
    }
    float s = 0.f, s2 = 0.f;
    #pragma unroll
    for (int p = 0; p < 18; ++p) { s += part[p]; s2 += part[p] * part[p]; }
    float m = s / 18.f;
    float var = s2 / 18.f - m * m;
    if (var < 0.f) var = 0.f;
    float inv = rsqrtf(var + 1e-6f);
    if (lane < 18) {
        float r = fmaf((part[lane] - m) * inv, g[lane], b[lane]);
        vf[o * 32 + 11 + lane] = fmaxf(r, 0.f);
    }
}

// ---------------- argmin: one wave per query ----------------
__global__ __launch_bounds__(256) void argmin_k(
    const float* __restrict__ v, const float* __restrict__ vert,
    int* __restrict__ idx) {
    __shared__ float4 sv[NV_];
    int tid = threadIdx.x;
    for (int i = tid; i < NV_; i += 256) {
        float x = vert[i * 3 + 0], y = vert[i * 3 + 1], z = vert[i * 3 + 2];
        float pn = __fadd_rn(__fadd_rn(__fmul_rn(x, x), __fmul_rn(y, y)), __fmul_rn(z, z));
        sv[i] = make_float4(x, y, z, pn);
    }
    __syncthreads();
    int lane = tid & 63;
    int q = blockIdx.x * 4 + (tid >> 6);
    float vx = v[q * 3 + 0], vy = v[q * 3 + 1], vz = v[q * 3 + 2];
    float vn = __fadd_rn(__fadd_rn(__fmul_rn(vx, vx), __fmul_rn(vy, vy)), __fmul_rn(vz, vz));
    float best = 3.4e38f;
    int bi = 0;
    // d2 = (|v|^2 + |p|^2) - 2*(v.p), np-rounding preserved (no fma contraction)
    for (int p = lane; p < NV_; p += 64) {
        float4 pv = sv[p];
        float dot = __fadd_rn(__fadd_rn(__fmul_rn(vx, pv.x), __fmul_rn(vy, pv.y)), __fmul_rn(vz, pv.z));
        float d2 = __fsub_rn(__fadd_rn(vn, pv.w), __fmul_rn(2.f, dot));
        if (d2 < best) { best = d2; bi = p; }   // ascending p => keeps smallest idx on ties
    }
    #pragma unroll
    for (int off = 1; off < 64; off <<= 1) {
        float od = __shfl_xor(best, off, 64);
        int   oi = __shfl_xor(bi, off, 64);
        if (od < best || (od == best && oi < bi)) { best = od; bi = oi; }
    }
    if (lane == 0) idx[q] = bi;
}

// ---------------- weight f32 -> bf16 (with row zero-padding) ----------------
// wb layout (shorts): [0,9216) atw1 ; [9216,10752) atw2 pad to 16 rows ;
//                     [10752,19968) fcw1 ; [19968,24576) fcw2 pad to 48 rows
__global__ void wcvt_k(const float* __restrict__ atw1, const float* __restrict__ atw2,
                       const float* __restrict__ fcw1, const float* __restrict__ fcw2,
                       short* __restrict__ wb) {
    int i = blockIdx.x * 256 + threadIdx.x;   // grid 96 -> 24576
    short v = 0;
    if (i < 9216) v = f2b(atw1[i]);
    else if (i < 10752) { int j = i - 9216; v = (j < 576) ? f2b(atw2[j]) : (short)0; }
    else if (i < 19968) v = f2b(fcw1[i - 10752]);
    else { int j = i - 19968; v = (j < 3840) ? f2b(fcw2[j]) : (short)0; }
    wb[i] = v;
}

// ---------------- MFMA MLP: 16 queries per wave, 64 per block ----------------
#define YP 104   // padded LDS row stride in shorts (2-way bank aliasing only)

__global__ __launch_bounds__(256) void mlp_mfma_k(
    const int* __restrict__ idx,
    const float* __restrict__ vvis, const float* __restrict__ qvis,
    const float* __restrict__ ixy, const float* __restrict__ fxy,
    const float* __restrict__ lat, const float* __restrict__ vf,
    const short* __restrict__ wb, float* __restrict__ out) {
    __shared__ short Y[64 * YP];
    __shared__ short Hb[64 * YP];
    __shared__ float A6[64 * 8];
    int t = threadIdx.x;
    int lane = t & 63, wave = t >> 6;
    int q0 = blockIdx.x * 64;

    // ---- y build: 4 lanes per query, bf16 into LDS; keep f32 copy in regs ----
    int ql = t >> 2, part = t & 3;
    int q = q0 + ql;
    int bi = idx[q];
    int bi2 = bi + HALF_V; if (bi2 >= NV_) bi2 -= NV_;
    const float* f  = vf + bi * 32;
    const float* ft = vf + bi2 * 32;
    float vis = vvis[bi], vist = vvis[bi2];
    short* yr = &Y[ql * YP];
    float myv[24];
    #pragma unroll
    for (int jj = 0; jj < 24; ++jj) {
        int j = part * 24 + jj;
        float val;
        if (j < 3)       val = ixy[q * 3 + j];
        else if (j < 11) val = fxy[q * 8 + j - 3];
        else if (j < 22) val = f[j - 11] * vis;
        else if (j < 33) val = ft[j - 22] * vist;
        else if (j < 51) val = f[11 + j - 33] * vis;
        else if (j < 69) val = ft[11 + j - 51] * vist;
        else if (j < 93) val = lat[q * 24 + j - 69];
        else if (j == 93) val = qvis[q];
        else if (j == 94) val = vis;
        else              val = vist;
        myv[jj] = val;
        yr[j] = f2b(val);
    }
    __syncthreads();

    int nloc = lane & 15, quad = lane >> 4;
    const short* Ya = &Y[(wave * 16 + nloc) * YP];
    const short* Ha = &Hb[(wave * 16 + nloc) * YP];
    int hrow = wave * 16 + quad * 4;    // C-layout row base for this lane

    // ---- GEMM1: H = relu(Y x atw1^T) ----
    f32x4 acc[6];
    #pragma unroll
    for (int nt = 0; nt < 6; ++nt) acc[nt] = (f32x4){0.f, 0.f, 0.f, 0.f};
    #pragma unroll
    for (int k0 = 0; k0 < 96; k0 += 32) {
        bf16x8 a = *(const bf16x8*)(Ya + k0 + quad * 8);
        #pragma unroll
        for (int nt = 0; nt < 6; ++nt) {
            bf16x8 b = *(const bf16x8*)(wb + (nt * 16 + nloc) * 96 + k0 + quad * 8);
            acc[nt] = __builtin_amdgcn_mfma_f32_16x16x32_bf16(a, b, acc[nt], 0, 0, 0);
        }
    }
    #pragma unroll
    for (int nt = 0; nt < 6; ++nt)
        #pragma unroll
        for (int r = 0; r < 4; ++r)
            Hb[(hrow + r) * YP + nt * 16 + nloc] = f2b(fmaxf(acc[nt][r], 0.f));
    __syncthreads();

    // ---- GEMM2: at6 = sigmoid(H x atw2^T) ----
    {
        const short* w2 = wb + 9216;
        f32x4 a2 = (f32x4){0.f, 0.f, 0.f, 0.f};
        #pragma unroll
        for (int k0 = 0; k0 < 96; k0 += 32) {
            bf16x8 a = *(const bf16x8*)(Ha + k0 + quad * 8);
            bf16x8 b = *(const bf16x8*)(w2 + nloc * 96 + k0 + quad * 8);
            a2 = __builtin_amdgcn_mfma_f32_16x16x32_bf16(a, b, a2, 0, 0, 0);
        }
        if (nloc < 6) {
            #pragma unroll
            for (int r = 0; r < 4; ++r)
                A6[(hrow + r) * 8 + nloc] = 1.f / (1.f + expf(-a2[r]));
        }
    }
    __syncthreads();

    // ---- scale Y in place from f32 register copy ----
    {
        const float* ap = &A6[ql * 8];
        #pragma unroll
        for (int jj = 0; jj < 24; ++jj) {
            int j = part * 24 + jj;
            float s;
            if (j < 11)      s = ap[0];
            else if (j < 22) s = ap[1];
            else if (j < 33) s = ap[2];
            else if (j < 51) s = ap[3];
            else if (j < 69) s = ap[4];
            else if (j < 93) s = ap[5];
            else             s = 1.f;
            yr[j] = f2b(myv[jj] * s);
        }
    }
    __syncthreads();

    // ---- GEMM3: H2 = relu(Y2 x fcw1^T) ----
    {
        const short* w3 = wb + 10752;
        #pragma unroll
        for (int nt = 0; nt < 6; ++nt) acc[nt] = (f32x4){0.f, 0.f, 0.f, 0.f};
        #pragma unroll
        for (int k0 = 0; k0 < 96; k0 += 32) {
            bf16x8 a = *(const bf16x8*)(Ya + k0 + quad * 8);
            #pragma unroll
            for (int nt = 0; nt < 6; ++nt) {
                bf16x8 b = *(const bf16x8*)(w3 + (nt * 16 + nloc) * 96 + k0 + quad * 8);
                acc[nt] = __builtin_amdgcn_mfma_f32_16x16x32_bf16(a, b, acc[nt], 0, 0, 0);
            }
        }
        #pragma unroll
        for (int nt = 0; nt < 6; ++nt)
            #pragma unroll
            for (int r = 0; r < 4; ++r)
                Hb[(hrow + r) * YP + nt * 16 + nloc] = f2b(fmaxf(acc[nt][r], 0.f));
    }
    __syncthreads();

    // ---- GEMM4: OUT = H2 x fcw2^T ----
    {
        const short* w4 = wb + 19968;
        f32x4 oacc[3];
        #pragma unroll
        for (int nt = 0; nt < 3; ++nt) oacc[nt] = (f32x4){0.f, 0.f, 0.f, 0.f};
        #pragma unroll
        for (int k0 = 0; k0 < 96; k0 += 32) {
            bf16x8 a = *(const bf16x8*)(Ha + k0 + quad * 8);
            #pragma unroll
            for (int nt = 0; nt < 3; ++nt) {
                bf16x8 b = *(const bf16x8*)(w4 + (nt * 16 + nloc) * 96 + k0 + quad * 8);
                oacc[nt] = __builtin_amdgcn_mfma_f32_16x16x32_bf16(a, b, oacc[nt], 0, 0, 0);
            }
        }
        #pragma unroll
        for (int nt = 0; nt < 3; ++nt) {
            int oc = nt * 16 + nloc;
            if (oc < 40) {
                #pragma unroll
                for (int r = 0; r < 4; ++r)
                    out[(q0 + hrow + r) * 40 + oc] = oacc[nt][r];
            }
        }
    }
}

extern "C" void kernel_launch(void* const* d_in, const int* in_sizes, int n_in,
                              void* d_out, int out_size, void* d_ws, size_t ws_size,
                              hipStream_t stream) {
    const float* vert_xy = (const float*)d_in[0];
    const float* ft1     = (const float*)d_in[1];
    const float* ft_xy   = (const float*)d_in[2];
    const float* vert    = (const float*)d_in[3];
    const float* v       = (const float*)d_in[4];
    const float* vvis    = (const float*)d_in[5];
    const float* qvis    = (const float*)d_in[6];
    const float* ixy     = (const float*)d_in[7];
    const float* img     = (const float*)d_in[8];
    const float* lat     = (const float*)d_in[9];
    const float* fcw1    = (const float*)d_in[10];
    const float* fcw2    = (const float*)d_in[11];
    const float* atw1    = (const float*)d_in[12];
    const float* atw2    = (const float*)d_in[13];
    const float* gtw1    = (const float*)d_in[14];
    const float* gtg1    = (const float*)d_in[15];
    const float* gtb1    = (const float*)d_in[16];
    const float* gtw2    = (const float*)d_in[17];
    const float* gtg2    = (const float*)d_in[18];
    const float* gtb2    = (const float*)d_in[19];
    const float* c3w1    = (const float*)d_in[20];
    const float* c3g1    = (const float*)d_in[21];
    const float* c3b1    = (const float*)d_in[22];
    const float* c3w2    = (const float*)d_in[23];
    const float* c3g2    = (const float*)d_in[24];
    const float* c3b2    = (const float*)d_in[25];
    const float* c4w1    = (const float*)d_in[26];
    const float* c4g1    = (const float*)d_in[27];
    const float* c4b1    = (const float*)d_in[28];
    const float* c4w2    = (const float*)d_in[29];
    const float* c4g2    = (const float*)d_in[30];
    const float* c4b2    = (const float*)d_in[31];
    float* out = (float*)d_out;
    float* ws  = (float*)d_ws;
    float* stats = ws + WS_STATS;
    float* gfc   = ws + WS_GFC;
    float* gth   = ws + WS_GTH;
    float* vfb   = ws + WS_VF;
    float* c3a   = ws + WS_C3A;
    float* c3bb  = ws + WS_C3B;
    float* c4a   = ws + WS_C4A;
    float* c4bb  = ws + WS_C4B;
    float* part_c3 = ws + WS_C4A;            // c4a not live during c3 chain
    short* wbf     = (short*)(ws + WS_C3A);  // c3a dead after c3 conv2 (24576 shorts)
    float* part_c4 = ws + WS_C3B;            // c3bb dead after apool(c3)
    int*   idx   = (int*)(ws + WS_C4B);      // c4bb dead after apool(c4)

    feat_sample_k<<<25, 64, 0, stream>>>(vert_xy, img, ft1, vfb);

    // c3 chain: ft1 (8,64,64) -> (21) -> (42) -> pool -> gfc cols 9..17
    conv2_k<7><<<dim3(8, 3), 256, 0, stream>>>(ft1, c3w1, c3a, part_c3, 8, 64, 64);
    ln_finalize_k<<<1, 64, 0, stream>>>(part_c3, stats + 0, 21, 8, 1.f / 4096.f);
    ln_apply_k<<<21 * 16, 256, 0, stream>>>(c3a, stats + 0, c3g1, c3b1, 4096);
    conv2_k<7><<<dim3(8, 6), 256, 0, stream>>>(c3a, c3w2, c3bb, part_c3, 21, 64, 64);
    wcvt_k<<<96, 256, 0, stream>>>(atw1, atw2, fcw1, fcw2, wbf);  // c3a now dead
    ln_finalize_k<<<1, 64, 0, stream>>>(part_c3, stats + 128, 42, 8, 1.f / 4096.f);
    ln_apply_k<<<42 * 16, 256, 0, stream>>>(c3bb, stats + 128, c3g2, c3b2, 4096);
    apool3_k<<<42 * 9, 256, 0, stream>>>(c3bb, gfc, 64, 64, 9);

    // c4 chain: img (3,256,256) -> (21) -> (42) -> pool -> gfc cols 0..8
    conv2_k<7><<<dim3(128, 3), 256, 0, stream>>>(img, c4w1, c4a, part_c4, 3, 256, 256);
    ln_finalize_k<<<1, 64, 0, stream>>>(part_c4, stats + 256, 21, 128, 1.f / 65536.f);
    ln_apply_k<<<21 * 256, 256, 0, stream>>>(c4a, stats + 256, c4g1, c4b1, 65536);
    conv2_k<7><<<dim3(128, 6), 256, 0, stream>>>(c4a, c4w2, c4bb, part_c4, 21, 256, 256);
    ln_finalize_k<<<1, 64, 0, stream>>>(part_c4, stats + 384, 42, 128, 1.f / 65536.f);
    ln_apply_k<<<42 * 256, 256, 0, stream>>>(c4bb, stats + 384, c4g2, c4b2, 65536);
    apool3_k<<<42 * 9, 256, 0, stream>>>(c4bb, gfc, 256, 256, 0);

    // argmin AFTER apool(c4): idx[] overlaps the now-dead c4bb region
    argmin_k<<<NQ_ / 4, 256, 0, stream>>>(v, vert, idx);

    // global-token conv1d stack -> vf cols 11..28
    gt1_k<<<779, 64, 0, stream>>>(gfc, gtw1, gtg1, gtb1, gth);
    gt2_k<<<1558, 64, 0, stream>>>(gth, gtw2, gtg2, gtb2, vfb);

    // fused per-query MFMA MLP path
    mlp_mfma_k<<<NQ_ / 64, 256, 0, stream>>>(idx, vvis, qvis, ixy, ft_xy, lat, vfb,
                                             wbf, out);
}

// Round 5
// 402.021 us; speedup vs baseline: 1.9904x; 1.0057x over previous
//
#include <hip/hip_runtime.h>
#include <hip/hip_bf16.h>
#include <math.h>

#define NQ_    65536
#define NV_    1558
#define HALF_V 779
#define VSPLIT 4
#define VCHUNK 390   // ceil(1558/4); ranges ascending in p

// ws layout in floats (total 4,452,352 floats = 17.8 MB)
#define WS_STATS 0          //   512
#define WS_GFC   512        //   768
#define WS_GTH   1280       // 14080
#define WS_VF    15360      // 50176 (1558*32)
#define WS_C3A   65536      // 86016  (reused: bf16 weights after c3 conv2)
#define WS_C3B   151552     // 172032 (tail reused for c4 stat partials)
#define WS_C4A   323584     // 1376256 (head reused for c3 stat partials)
#define WS_C4B   1699840    // 2752512 (reused after apool(c4): idx/bestd/besti/vert4)

typedef __attribute__((ext_vector_type(8))) short bf16x8;
typedef __attribute__((ext_vector_type(4))) float f32x4;

__device__ __forceinline__ short f2b(float x) {
    union { __hip_bfloat16 h; short s; } u; u.h = __float2bfloat16(x); return u.s;
}

// ---------------- bilinear feature sampling (vertices) ----------------
__device__ __forceinline__ void bsample(const float* __restrict__ f, int C, int H, int W,
                                        float xn, float yn, float* __restrict__ o) {
    float x = (xn + 1.f) * 0.5f * (float)(W - 1);
    float y = (yn + 1.f) * 0.5f * (float)(H - 1);
    float x0f = floorf(x), y0f = floorf(y);
    float wx = x - x0f, wy = y - y0f;
    int x0 = (int)fminf(fmaxf(x0f, 0.f), (float)(W - 1));
    int x1 = (int)fminf(fmaxf(x0f + 1.f, 0.f), (float)(W - 1));
    int y0 = (int)fminf(fmaxf(y0f, 0.f), (float)(H - 1));
    int y1 = (int)fminf(fmaxf(y0f + 1.f, 0.f), (float)(H - 1));
    for (int c = 0; c < C; ++c) {
        const float* b = f + c * H * W;
        float v00 = b[y0 * W + x0], v01 = b[y0 * W + x1];
        float v10 = b[y1 * W + x0], v11 = b[y1 * W + x1];
        o[c] = v00 * (1.f - wx) * (1.f - wy) + v01 * wx * (1.f - wy)
             + v10 * (1.f - wx) * wy       + v11 * wx * wy;
    }
}

__global__ void feat_sample_k(const float* __restrict__ vert_xy,
                              const float* __restrict__ img,
                              const float* __restrict__ ft1,
                              float* __restrict__ vf) {
    int v = blockIdx.x * 64 + threadIdx.x;
    if (v >= NV_) return;
    float xn = vert_xy[v * 2 + 0], yn = vert_xy[v * 2 + 1];
    float tmp[8];
    bsample(img, 3, 256, 256, xn, yn, tmp);
    float* o = vf + v * 32;
    o[0] = tmp[0]; o[1] = tmp[1]; o[2] = tmp[2];
    bsample(ft1, 8, 64, 64, xn, yn, tmp);
    #pragma unroll
    for (int c = 0; c < 8; ++c) o[3 + c] = tmp[c];
}

// ---------------- conv2d 3x3 pad1: 2 pixels x CB channels per thread,
// ---------------- fused per-(channel,block) sum/sumsq partials ----------------
template <int CB>
__global__ __launch_bounds__(256) void conv2_k(
    const float* __restrict__ in, const float* __restrict__ w,
    float* __restrict__ out, float* __restrict__ part,
    int Cin, int H, int W) {
    int c0 = blockIdx.y * CB;
    int tid = threadIdx.x;
    int px0 = (blockIdx.x * 256 + tid) * 2;
    int HW = H * W;
    int y = px0 / W, x = px0 % W;      // x is even
    float acc0[CB], acc1[CB];
    #pragma unroll
    for (int j = 0; j < CB; ++j) { acc0[j] = 0.f; acc1[j] = 0.f; }
    const float* wbase = w + c0 * Cin * 9;
    #pragma unroll 2
    for (int ci = 0; ci < Cin; ++ci) {
        const float* ip = in + ci * HW;
        float win[3][4];
        #pragma unroll
        for (int r = 0; r < 3; ++r) {
            int yy = y + r - 1;
            bool okY = (yy >= 0) && (yy < H);
            const float* rp = ip + yy * W;
            float2 m = okY ? *(const float2*)(rp + x) : make_float2(0.f, 0.f);
            win[r][1] = m.x; win[r][2] = m.y;
            win[r][0] = (okY && x > 0)     ? rp[x - 1] : 0.f;
            win[r][3] = (okY && x + 2 < W) ? rp[x + 2] : 0.f;
        }
        const float* wc = wbase + ci * 9;
        #pragma unroll
        for (int j = 0; j < CB; ++j) {
            const float* wj = wc + j * Cin * 9;
            #pragma unroll
            for (int r = 0; r < 3; ++r) {
                float w0 = wj[r * 3 + 0], w1 = wj[r * 3 + 1], w2 = wj[r * 3 + 2];
                acc0[j] = fmaf(w0, win[r][0], fmaf(w1, win[r][1], fmaf(w2, win[r][2], acc0[j])));
                acc1[j] = fmaf(w0, win[r][1], fmaf(w1, win[r][2], fmaf(w2, win[r][3], acc1[j])));
            }
        }
    }
    #pragma unroll
    for (int j = 0; j < CB; ++j)
        *(float2*)(out + (c0 + j) * HW + px0) = make_float2(acc0[j], acc1[j]);

    // fused stats: per-(channel, block) sum / sumsq
    __shared__ float sred[4][CB][2];
    int lane = tid & 63, wave = tid >> 6;
    #pragma unroll
    for (int j = 0; j < CB; ++j) {
        float s = acc0[j] + acc1[j];
        float qq = acc0[j] * acc0[j] + acc1[j] * acc1[j];
        #pragma unroll
        for (int off = 1; off < 64; off <<= 1) {
            s  += __shfl_xor(s, off, 64);
            qq += __shfl_xor(qq, off, 64);
        }
        if (lane == 0) { sred[wave][j][0] = s; sred[wave][j][1] = qq; }
    }
    __syncthreads();
    if (tid < CB) {
        float s = sred[0][tid][0] + sred[1][tid][0] + sred[2][tid][0] + sred[3][tid][0];
        float qq = sred[0][tid][1] + sred[1][tid][1] + sred[2][tid][1] + sred[3][tid][1];
        int c = c0 + tid;
        part[(c * gridDim.x + blockIdx.x) * 2 + 0] = s;
        part[(c * gridDim.x + blockIdx.x) * 2 + 1] = qq;
    }
}

__global__ void ln_finalize_k(const float* __restrict__ part, float* __restrict__ stats,
                              int C, int nb, float invHW) {
    int c = threadIdx.x;
    if (c >= C) return;
    float s = 0.f, s2 = 0.f;
    for (int i = 0; i < nb; ++i) {
        s  += part[(c * nb + i) * 2 + 0];
        s2 += part[(c * nb + i) * 2 + 1];
    }
    float m = s * invHW;
    float var = s2 * invHW - m * m;
    if (var < 0.f) var = 0.f;
    stats[c * 2 + 0] = m;
    stats[c * 2 + 1] = rsqrtf(var + 1e-6f);
}

__global__ __launch_bounds__(256) void ln_apply_k(
    float* __restrict__ buf, const float* __restrict__ stats,
    const float* __restrict__ g, const float* __restrict__ b, int HW) {
    int i = blockIdx.x * 256 + threadIdx.x;
    int c = i / HW;      // HW is a power of two
    int hw = i % HW;
    float m = stats[c * 2], inv = stats[c * 2 + 1];
    float x = buf[i];
    float r = fmaf((x - m) * inv, g[hw], b[hw]);
    buf[i] = fmaxf(r, 0.f);
}

// ---------------- adaptive 3x3 avg pool -> gf_cat[c][colOff + bin] ----------------
__global__ __launch_bounds__(256) void apool3_k(const float* __restrict__ in,
                                                float* __restrict__ gfc,
                                                int H, int W, int colOff) {
    int c = (int)blockIdx.x / 9;
    int bin = (int)blockIdx.x % 9;
    int bh = bin / 3, bw = bin % 3;
    int hs = bh * H / 3, he = ((bh + 1) * H + 2) / 3;
    int wsx = bw * W / 3, we = ((bw + 1) * W + 2) / 3;
    int rw = we - wsx, rh = he - hs, n = rw * rh;
    const float* b = in + c * H * W;
    float s = 0.f;
    for (int t = threadIdx.x; t < n; t += 256) {
        int iy = t / rw, ix = t % rw;
        s += b[(hs + iy) * W + (wsx + ix)];
    }
    __shared__ float rs[256];
    rs[threadIdx.x] = s;
    __syncthreads();
    for (int st = 128; st > 0; st >>= 1) {
        if (threadIdx.x < st) rs[threadIdx.x] += rs[threadIdx.x + st];
        __syncthreads();
    }
    if (threadIdx.x == 0) gfc[c * 18 + colOff + bin] = rs[0] / (float)n;
}

// ---------------- conv1d (42->779) + LN(18) + relu ----------------
__global__ __launch_bounds__(64) void gt1_k(const float* __restrict__ gfc,
                                            const float* __restrict__ w,
                                            const float* __restrict__ g,
                                            const float* __restrict__ b,
                                            float* __restrict__ outh) {
    int o = blockIdx.x;     // 779
    int p = threadIdx.x;
    __shared__ float vals[18];
    if (p < 18) {
        float acc = 0.f;
        const float* wo = w + o * 42 * 3;
        for (int c = 0; c < 42; ++c) {
            const float* gr = gfc + c * 18;
            #pragma unroll
            for (int k = 0; k < 3; ++k) {
                int pk = p + k - 1;
                if (pk >= 0 && pk < 18) acc = fmaf(wo[c * 3 + k], gr[pk], acc);
            }
        }
        vals[p] = acc;
    }
    __syncthreads();
    if (p < 18) {
        float s = 0.f, s2 = 0.f;
        #pragma unroll
        for (int j = 0; j < 18; ++j) { float x = vals[j]; s += x; s2 += x * x; }
        float m = s / 18.f;
        float var = s2 / 18.f - m * m;
        if (var < 0.f) var = 0.f;
        float inv = rsqrtf(var + 1e-6f);
        float r = fmaf((vals[p] - m) * inv, g[p], b[p]);
        outh[o * 18 + p] = fmaxf(r, 0.f);
    }
}

// ---------------- conv1d (779->1558) + LN(18) + relu -> vf cols 11..28 ----------------
// 4 waves per block; each wave covers a contiguous quarter of the 779 channels.
__global__ __launch_bounds__(256) void gt2_k(const float* __restrict__ h,
                                             const float* __restrict__ w,
                                             const float* __restrict__ g,
                                             const float* __restrict__ b,
                                             float* __restrict__ vf) {
    int o = blockIdx.x;     // 1558
    int t = threadIdx.x, lane = t & 63, wave = t >> 6;
    __shared__ float red[4][18];
    float part[18];
    #pragma unroll
    for (int p = 0; p < 18; ++p) part[p] = 0.f;
    int c0 = wave * 195;
    int c1 = c0 + 195; if (c1 > HALF_V) c1 = HALF_V;
    for (int c = c0 + lane; c < c1; c += 64) {
        const float* wr = w + (o * HALF_V + c) * 3;
        float w0 = wr[0], w1 = wr[1], w2 = wr[2];
        const float* hr = h + c * 18;
        float hv[18];
        #pragma unroll
        for (int p = 0; p < 18; ++p) hv[p] = hr[p];
        #pragma unroll
        for (int p = 0; p < 18; ++p) {
            float a = w1 * hv[p];
            if (p > 0)  a = fmaf(w0, hv[p - 1], a);
            if (p < 17) a = fmaf(w2, hv[p + 1], a);
            part[p] += a;
        }
    }
    #pragma unroll
    for (int p = 0; p < 18; ++p) {
        float vv = part[p];
        #pragma unroll
        for (int off = 32; off > 0; off >>= 1) vv += __shfl_xor(vv, off, 64);
        part[p] = vv;
    }
    if (lane == 0) {
        #pragma unroll
        for (int p = 0; p < 18; ++p) red[wave][p] = part[p];
    }
    __syncthreads();
    if (t < 18) {
        float s = red[0][t] + red[1][t] + red[2][t] + red[3][t];
        red[0][t] = s;
    }
    __syncthreads();
    if (t < 18) {
        float s = 0.f, s2 = 0.f;
        #pragma unroll
        for (int j = 0; j < 18; ++j) { float x = red[0][j]; s += x; s2 += x * x; }
        float m = s / 18.f;
        float var = s2 / 18.f - m * m;
        if (var < 0.f) var = 0.f;
        float inv = rsqrtf(var + 1e-6f);
        float r = fmaf((red[0][t] - m) * inv, g[t], b[t]);
        vf[o * 32 + 11 + t] = fmaxf(r, 0.f);
    }
}

// ---------------- argmin: one THREAD per query, wave-uniform vertex scan ----------------
__global__ void vprep_k(const float* __restrict__ vert, float4* __restrict__ v4) {
    int i = blockIdx.x * 64 + threadIdx.x;
    if (i >= NV_) return;
    float x = vert[i * 3 + 0], y = vert[i * 3 + 1], z = vert[i * 3 + 2];
    float pn = __fadd_rn(__fadd_rn(__fmul_rn(x, x), __fmul_rn(y, y)), __fmul_rn(z, z));
    v4[i] = make_float4(x, y, z, pn);
}

__global__ __launch_bounds__(256) void argmin_part_k(
    const float* __restrict__ v, const float4* __restrict__ v4,
    float* __restrict__ bestd, int* __restrict__ besti) {
    int q = blockIdx.x * 256 + threadIdx.x;
    int r = blockIdx.y;
    int p0 = r * VCHUNK;
    int p1 = p0 + VCHUNK; if (p1 > NV_) p1 = NV_;
    float vx = v[q * 3 + 0], vy = v[q * 3 + 1], vz = v[q * 3 + 2];
    float vn = __fadd_rn(__fadd_rn(__fmul_rn(vx, vx), __fmul_rn(vy, vy)), __fmul_rn(vz, vz));
    float best = 3.4e38f;
    int bi = p0;
    // d2 = (|v|^2 + |p|^2) - 2*(v.p); np rounding preserved (no fma contraction).
    // v4[p] is wave-uniform -> scalar K$ loads; strict < keeps smallest p on ties.
    #pragma unroll 4
    for (int p = p0; p < p1; ++p) {
        float4 pv = v4[p];
        float dot = __fadd_rn(__fadd_rn(__fmul_rn(vx, pv.x), __fmul_rn(vy, pv.y)), __fmul_rn(vz, pv.z));
        float d2 = __fsub_rn(__fadd_rn(vn, pv.w), __fmul_rn(2.f, dot));
        if (d2 < best) { best = d2; bi = p; }
    }
    bestd[r * NQ_ + q] = best;
    besti[r * NQ_ + q] = bi;
}

__global__ __launch_bounds__(256) void argmin_comb_k(
    const float* __restrict__ bestd, const int* __restrict__ besti,
    int* __restrict__ idx) {
    int q = blockIdx.x * 256 + threadIdx.x;
    float best = bestd[q];
    int bi = besti[q];
    #pragma unroll
    for (int r = 1; r < VSPLIT; ++r) {
        float d = bestd[r * NQ_ + q];
        int i2 = besti[r * NQ_ + q];
        if (d < best) { best = d; bi = i2; }   // ranges ascend in p; strict < keeps first min
    }
    idx[q] = bi;
}

// ---------------- weight f32 -> bf16 (with row zero-padding) ----------------
// wb layout (shorts): [0,9216) atw1 ; [9216,10752) atw2 pad to 16 rows ;
//                     [10752,19968) fcw1 ; [19968,24576) fcw2 pad to 48 rows
__global__ void wcvt_k(const float* __restrict__ atw1, const float* __restrict__ atw2,
                       const float* __restrict__ fcw1, const float* __restrict__ fcw2,
                       short* __restrict__ wb) {
    int i = blockIdx.x * 256 + threadIdx.x;   // grid 96 -> 24576
    short v = 0;
    if (i < 9216) v = f2b(atw1[i]);
    else if (i < 10752) { int j = i - 9216; v = (j < 576) ? f2b(atw2[j]) : (short)0; }
    else if (i < 19968) v = f2b(fcw1[i - 10752]);
    else { int j = i - 19968; v = (j < 3840) ? f2b(fcw2[j]) : (short)0; }
    wb[i] = v;
}

// ---------------- MFMA MLP: 16 queries per wave, 64 per block ----------------
#define YP 104   // padded LDS row stride in shorts (2-way bank aliasing only)

__global__ __launch_bounds__(256) void mlp_mfma_k(
    const int* __restrict__ idx,
    const float* __restrict__ vvis, const float* __restrict__ qvis,
    const float* __restrict__ ixy, const float* __restrict__ fxy,
    const float* __restrict__ lat, const float* __restrict__ vf,
    const short* __restrict__ wb, float* __restrict__ out) {
    __shared__ short Y[64 * YP];
    __shared__ short Hb[64 * YP];
    __shared__ float A6[64 * 8];
    int t = threadIdx.x;
    int lane = t & 63, wave = t >> 6;
    int q0 = blockIdx.x * 64;

    // ---- y build: 4 lanes per query, bf16 into LDS; keep f32 copy in regs ----
    int ql = t >> 2, part = t & 3;
    int q = q0 + ql;
    int bi = idx[q];
    int bi2 = bi + HALF_V; if (bi2 >= NV_) bi2 -= NV_;
    const float* f  = vf + bi * 32;
    const float* ft = vf + bi2 * 32;
    float vis = vvis[bi], vist = vvis[bi2];
    short* yr = &Y[ql * YP];
    float myv[24];
    #pragma unroll
    for (int jj = 0; jj < 24; ++jj) {
        int j = part * 24 + jj;
        float val;
        if (j < 3)       val = ixy[q * 3 + j];
        else if (j < 11) val = fxy[q * 8 + j - 3];
        else if (j < 22) val = f[j - 11] * vis;
        else if (j < 33) val = ft[j - 22] * vist;
        else if (j < 51) val = f[11 + j - 33] * vis;
        else if (j < 69) val = ft[11 + j - 51] * vist;
        else if (j < 93) val = lat[q * 24 + j - 69];
        else if (j == 93) val = qvis[q];
        else if (j == 94) val = vis;
        else              val = vist;
        myv[jj] = val;
        yr[j] = f2b(val);
    }
    __syncthreads();

    int nloc = lane & 15, quad = lane >> 4;
    const short* Ya = &Y[(wave * 16 + nloc) * YP];
    const short* Ha = &Hb[(wave * 16 + nloc) * YP];
    int hrow = wave * 16 + quad * 4;    // C-layout row base for this lane

    // ---- GEMM1: H = relu(Y x atw1^T) ----
    f32x4 acc[6];
    #pragma unroll
    for (int nt = 0; nt < 6; ++nt) acc[nt] = (f32x4){0.f, 0.f, 0.f, 0.f};
    #pragma unroll
    for (int k0 = 0; k0 < 96; k0 += 32) {
        bf16x8 a = *(const bf16x8*)(Ya + k0 + quad * 8);
        #pragma unroll
        for (int nt = 0; nt < 6; ++nt) {
            bf16x8 b = *(const bf16x8*)(wb + (nt * 16 + nloc) * 96 + k0 + quad * 8);
            acc[nt] = __builtin_amdgcn_mfma_f32_16x16x32_bf16(a, b, acc[nt], 0, 0, 0);
        }
    }
    #pragma unroll
    for (int nt = 0; nt < 6; ++nt)
        #pragma unroll
        for (int r = 0; r < 4; ++r)
            Hb[(hrow + r) * YP + nt * 16 + nloc] = f2b(fmaxf(acc[nt][r], 0.f));
    __syncthreads();

    // ---- GEMM2: at6 = sigmoid(H x atw2^T) ----
    {
        const short* w2 = wb + 9216;
        f32x4 a2 = (f32x4){0.f, 0.f, 0.f, 0.f};
        #pragma unroll
        for (int k0 = 0; k0 < 96; k0 += 32) {
            bf16x8 a = *(const bf16x8*)(Ha + k0 + quad * 8);
            bf16x8 b = *(const bf16x8*)(w2 + nloc * 96 + k0 + quad * 8);
            a2 = __builtin_amdgcn_mfma_f32_16x16x32_bf16(a, b, a2, 0, 0, 0);
        }
        if (nloc < 6) {
            #pragma unroll
            for (int r = 0; r < 4; ++r)
                A6[(hrow + r) * 8 + nloc] = 1.f / (1.f + expf(-a2[r]));
        }
    }
    __syncthreads();

    // ---- scale Y in place from f32 register copy ----
    {
        const float* ap = &A6[ql * 8];
        #pragma unroll
        for (int jj = 0; jj < 24; ++jj) {
            int j = part * 24 + jj;
            float s;
            if (j < 11)      s = ap[0];
            else if (j < 22) s = ap[1];
            else if (j < 33) s = ap[2];
            else if (j < 51) s = ap[3];
            else if (j < 69) s = ap[4];
            else if (j < 93) s = ap[5];
            else             s = 1.f;
            yr[j] = f2b(myv[jj] * s);
        }
    }
    __syncthreads();

    // ---- GEMM3: H2 = relu(Y2 x fcw1^T) ----
    {
        const short* w3 = wb + 10752;
        #pragma unroll
        for (int nt = 0; nt < 6; ++nt) acc[nt] = (f32x4){0.f, 0.f, 0.f, 0.f};
        #pragma unroll
        for (int k0 = 0; k0 < 96; k0 += 32) {
            bf16x8 a = *(const bf16x8*)(Ya + k0 + quad * 8);
            #pragma unroll
            for (int nt = 0; nt < 6; ++nt) {
                bf16x8 b = *(const bf16x8*)(w3 + (nt * 16 + nloc) * 96 + k0 + quad * 8);
                acc[nt] = __builtin_amdgcn_mfma_f32_16x16x32_bf16(a, b, acc[nt], 0, 0, 0);
            }
        }
        #pragma unroll
        for (int nt = 0; nt < 6; ++nt)
            #pragma unroll
            for (int r = 0; r < 4; ++r)
                Hb[(hrow + r) * YP + nt * 16 + nloc] = f2b(fmaxf(acc[nt][r], 0.f));
    }
    __syncthreads();

    // ---- GEMM4: OUT = H2 x fcw2^T ----
    {
        const short* w4 = wb + 19968;
        f32x4 oacc[3];
        #pragma unroll
        for (int nt = 0; nt < 3; ++nt) oacc[nt] = (f32x4){0.f, 0.f, 0.f, 0.f};
        #pragma unroll
        for (int k0 = 0; k0 < 96; k0 += 32) {
            bf16x8 a = *(const bf16x8*)(Ha + k0 + quad * 8);
            #pragma unroll
            for (int nt = 0; nt < 3; ++nt) {
                bf16x8 b = *(const bf16x8*)(w4 + (nt * 16 + nloc) * 96 + k0 + quad * 8);
                oacc[nt] = __builtin_amdgcn_mfma_f32_16x16x32_bf16(a, b, oacc[nt], 0, 0, 0);
            }
        }
        #pragma unroll
        for (int nt = 0; nt < 3; ++nt) {
            int oc = nt * 16 + nloc;
            if (oc < 40) {
                #pragma unroll
                for (int r = 0; r < 4; ++r)
                    out[(q0 + hrow + r) * 40 + oc] = oacc[nt][r];
            }
        }
    }
}

extern "C" void kernel_launch(void* const* d_in, const int* in_sizes, int n_in,
                              void* d_out, int out_size, void* d_ws, size_t ws_size,
                              hipStream_t stream) {
    const float* vert_xy = (const float*)d_in[0];
    const float* ft1     = (const float*)d_in[1];
    const float* ft_xy   = (const float*)d_in[2];
    const float* vert    = (const float*)d_in[3];
    const float* v       = (const float*)d_in[4];
    const float* vvis    = (const float*)d_in[5];
    const float* qvis    = (const float*)d_in[6];
    const float* ixy     = (const float*)d_in[7];
    const float* img     = (const float*)d_in[8];
    const float* lat     = (const float*)d_in[9];
    const float* fcw1    = (const float*)d_in[10];
    const float* fcw2    = (const float*)d_in[11];
    const float* atw1    = (const float*)d_in[12];
    const float* atw2    = (const float*)d_in[13];
    const float* gtw1    = (const float*)d_in[14];
    const float* gtg1    = (const float*)d_in[15];
    const float* gtb1    = (const float*)d_in[16];
    const float* gtw2    = (const float*)d_in[17];
    const float* gtg2    = (const float*)d_in[18];
    const float* gtb2    = (const float*)d_in[19];
    const float* c3w1    = (const float*)d_in[20];
    const float* c3g1    = (const float*)d_in[21];
    const float* c3b1    = (const float*)d_in[22];
    const float* c3w2    = (const float*)d_in[23];
    const float* c3g2    = (const float*)d_in[24];
    const float* c3b2    = (const float*)d_in[25];
    const float* c4w1    = (const float*)d_in[26];
    const float* c4g1    = (const float*)d_in[27];
    const float* c4b1    = (const float*)d_in[28];
    const float* c4w2    = (const float*)d_in[29];
    const float* c4g2    = (const float*)d_in[30];
    const float* c4b2    = (const float*)d_in[31];
    float* out = (float*)d_out;
    float* ws  = (float*)d_ws;
    float* stats = ws + WS_STATS;
    float* gfc   = ws + WS_GFC;
    float* gth   = ws + WS_GTH;
    float* vfb   = ws + WS_VF;
    float* c3a   = ws + WS_C3A;
    float* c3bb  = ws + WS_C3B;
    float* c4a   = ws + WS_C4A;
    float* c4bb  = ws + WS_C4B;
    float* part_c3 = ws + WS_C4A;            // c4a not live during c3 chain
    short* wbf     = (short*)(ws + WS_C3A);  // c3a dead after c3 conv2 (24576 shorts)
    float* part_c4 = ws + WS_C3B;            // c3bb dead after apool(c3)
    // after apool(c4), c4bb region is dead; carve argmin scratch out of it:
    int*    idx   = (int*)(ws + WS_C4B);                    // 65536 ints
    float*  bestd = ws + WS_C4B + 65536;                    // 4*65536 floats
    int*    besti = (int*)(ws + WS_C4B + 65536 + 262144);   // 4*65536 ints
    float4* vert4 = (float4*)(ws + WS_C4B + 65536 + 524288); // 1558 float4

    feat_sample_k<<<25, 64, 0, stream>>>(vert_xy, img, ft1, vfb);

    // c3 chain: ft1 (8,64,64) -> (21) -> (42) -> pool -> gfc cols 9..17
    conv2_k<7><<<dim3(8, 3), 256, 0, stream>>>(ft1, c3w1, c3a, part_c3, 8, 64, 64);
    ln_finalize_k<<<1, 64, 0, stream>>>(part_c3, stats + 0, 21, 8, 1.f / 4096.f);
    ln_apply_k<<<21 * 16, 256, 0, stream>>>(c3a, stats + 0, c3g1, c3b1, 4096);
    conv2_k<7><<<dim3(8, 6), 256, 0, stream>>>(c3a, c3w2, c3bb, part_c3, 21, 64, 64);
    wcvt_k<<<96, 256, 0, stream>>>(atw1, atw2, fcw1, fcw2, wbf);  // c3a now dead
    ln_finalize_k<<<1, 64, 0, stream>>>(part_c3, stats + 128, 42, 8, 1.f / 4096.f);
    ln_apply_k<<<42 * 16, 256, 0, stream>>>(c3bb, stats + 128, c3g2, c3b2, 4096);
    apool3_k<<<42 * 9, 256, 0, stream>>>(c3bb, gfc, 64, 64, 9);

    // c4 chain: img (3,256,256) -> (21) -> (42) -> pool -> gfc cols 0..8
    conv2_k<7><<<dim3(128, 3), 256, 0, stream>>>(img, c4w1, c4a, part_c4, 3, 256, 256);
    ln_finalize_k<<<1, 64, 0, stream>>>(part_c4, stats + 256, 21, 128, 1.f / 65536.f);
    ln_apply_k<<<21 * 256, 256, 0, stream>>>(c4a, stats + 256, c4g1, c4b1, 65536);
    conv2_k<7><<<dim3(128, 6), 256, 0, stream>>>(c4a, c4w2, c4bb, part_c4, 21, 256, 256);
    ln_finalize_k<<<1, 64, 0, stream>>>(part_c4, stats + 384, 42, 128, 1.f / 65536.f);
    ln_apply_k<<<42 * 256, 256, 0, stream>>>(c4bb, stats + 384, c4g2, c4b2, 65536);
    apool3_k<<<42 * 9, 256, 0, stream>>>(c4bb, gfc, 256, 256, 0);

    // argmin AFTER apool(c4): scratch overlaps the now-dead c4bb region
    vprep_k<<<25, 64, 0, stream>>>(vert, vert4);
    argmin_part_k<<<dim3(NQ_ / 256, VSPLIT), 256, 0, stream>>>(v, vert4, bestd, besti);
    argmin_comb_k<<<NQ_ / 256, 256, 0, stream>>>(bestd, besti, idx);

    // global-token conv1d stack -> vf cols 11..28
    gt1_k<<<779, 64, 0, stream>>>(gfc, gtw1, gtg1, gtb1, gth);
    gt2_k<<<1558, 256, 0, stream>>>(gth, gtw2, gtg2, gtb2, vfb);

    // fused per-query MFMA MLP path
    mlp_mfma_k<<<NQ_ / 64, 256, 0, stream>>>(idx, vvis, qvis, ixy, ft_xy, lat, vfb,
                                             wbf, out);
}